// Round 6
// baseline (807.621 us; speedup 1.0000x reference)
//
#include <hip/hip_runtime.h>
#include <hip/hip_bf16.h>

typedef unsigned short u16;
typedef unsigned int u32;
typedef __bf16 bf16x8 __attribute__((ext_vector_type(8)));
typedef float f32x4 __attribute__((ext_vector_type(4)));

#define MFMA16(a,b,c) __builtin_amdgcn_mfma_f32_16x16x32_bf16((a),(b),(c),0,0,0)

__device__ __forceinline__ u16 f2bf(float f){
  u32 u = __builtin_bit_cast(u32, f);
  u32 r = (u + 0x7fffu + ((u >> 16) & 1u)) >> 16;
  return (u16)r;
}
__device__ __forceinline__ float bf2f(u16 h){
  u32 u = ((u32)h) << 16;
  return __builtin_bit_cast(float, u);
}
__device__ __forceinline__ void splitbf(float x, u16& hi, u16& lo){
  hi = f2bf(x);
  lo = f2bf(x - bf2f(hi));
}
__device__ __forceinline__ void gload_lds16(const u16* g, u16* l){
  __builtin_amdgcn_global_load_lds((__attribute__((address_space(1))) void*)(g),
                                   (__attribute__((address_space(3))) void*)(l), 16, 0, 0);
}
__device__ __forceinline__ const u16* selu(const u16* barr, const u16* parr, int i){
  return (i < 128) ? (barr + (size_t)i*16384) : (parr + (size_t)(i-128)*16384);
}
__device__ __forceinline__ const float* self32(const float* barr, const float* parr, int i){
  return (i < 128) ? (barr + (size_t)i*16384) : (parr + (size_t)(i-128)*16384);
}
__device__ __forceinline__ float* slotp(float* p1, float* p2, int s){
  return (s < 762) ? (p1 + (size_t)s*8256) : (p2 + (size_t)(s-762)*8256);
}
__device__ __forceinline__ const float* slotpc(const float* p1, const float* p2, int s){
  return (s < 762) ? (p1 + (size_t)s*8256) : (p2 + (size_t)(s-762)*8256);
}

// ---------------- workspace layout (bytes) ----------------
constexpr size_t OF_HSBF   = 0;           // hs bf16 [2048][2048] (dead after gemm1)
constexpr size_t OF_WQKVBF = 8388608;     // Wqkv bf16 [3072][2048] (dead after gemm1)
constexpr size_t OF_WOBF   = 20971520;    // Wo bf16 [2048][2048]
constexpr size_t OF_QKV    = 29360128;    // qkv f32 [2048][3072] (dead after prep2a/vt)
constexpr size_t OF_QBF    = 54525952;    // raw q bf16 [16][2048][128]
constexpr size_t OF_KBF    = 62914560;    // raw k bf16 [4][2048][128]
constexpr size_t OF_VT     = 65011712;    // vT bf16 [4][128][2048]
constexpr size_t OF_QLB    = 67108864;    // softmax q bf16 [16][2048][128]
constexpr size_t OF_KLF    = 75497472;    // softmax k f32 [4][2048][128] (dead after prep2b)
constexpr size_t OF_KLB    = 79691776;    // softmax k bf16
constexpr size_t OF_GLF    = 81788928;    // gate f32 (dead after prep2a)
constexpr size_t OF_TINV   = 85983232;    // Tinv f32 (dead after prep2a)
constexpr size_t OF_WF     = 88080384;    // w f32 (dead after prep2b)
constexpr size_t OF_WB     = 92274688;    // w bf16
constexpr size_t OF_U0     = 94371840;    // u0 f32 [128][64][128]
constexpr size_t OF_SJ     = 111149056;   // S^T states bf16 [512][128][128]
constexpr size_t OF_OMIX   = 127926272;   // f32 [2048][2048] (written by olin, after scan)
constexpr size_t OF_OMIXB  = 144703488;   // bf16 [2048][2048] (written at end)
// scan operator buffers (D = M - I, f32 master + hi/lo bf16 mirrors; BT f32 + hi/lo):
// side A (written by prep2b, rounds 2,4):
constexpr size_t OF_ADF  = 102760448;             // D f32 8MB
constexpr size_t OF_ABTF = OF_OMIX;               // BT f32 8MB (omix dead until olin)
constexpr size_t OF_ADH  = OF_OMIX + 8388608;     // D hi 4MB
constexpr size_t OF_ADL  = OF_OMIX + 12582912;    // D lo 4MB
constexpr size_t OF_ADTH = OF_OMIXB;              // D^T hi 4MB
constexpr size_t OF_ADTL = OF_OMIXB + 4194304;    // D^T lo 4MB
constexpr size_t OF_ABTH = OF_KLF;                // BT hi 4MB
constexpr size_t OF_ABTL = OF_GLF;                // BT lo 4MB
// side B (written by rounds 1,3,5; read by comp/heads/expand):
constexpr size_t OF_BDF  = OF_QKV;                // 8MB
constexpr size_t OF_BBTF = OF_QKV + 8388608;      // 8MB
constexpr size_t OF_BDH  = OF_QKV + 16777216;     // 4MB
constexpr size_t OF_BDL  = OF_QKV + 20971520;     // 4MB (ends at OF_QBF)
constexpr size_t OF_BDTH = OF_HSBF;               // 4MB
constexpr size_t OF_BDTL = OF_HSBF + 4194304;     // 4MB
constexpr size_t OF_BBTH = OF_WQKVBF;             // 4MB
constexpr size_t OF_BBTL = OF_WQKVBF + 4194304;   // 4MB
// head-start states TT_h (16 x 128x128): f32 + hi/lo mirrors
constexpr size_t OF_TTF  = OF_TINV;               // 1MB
constexpr size_t OF_TTH  = OF_WQKVBF + 8388608;   // 512KB
constexpr size_t OF_TTL  = OF_WQKVBF + 8912896;   // 512KB
// op pool (16 slots: powers + group prefixes), overlaid on dead side-A DF region:
constexpr size_t OF_PDF  = OF_ADF;                // 1MB (16 x 64KB)
constexpr size_t OF_PBTF = OF_ADF + 1048576;      // 1MB
constexpr size_t OF_PDH  = OF_ADF + 2097152;      // 512KB
constexpr size_t OF_PDL  = OF_ADF + 2621440;
constexpr size_t OF_PDTH = OF_ADF + 3145728;
constexpr size_t OF_PDTL = OF_ADF + 3670016;
constexpr size_t OF_PBTH = OF_ADF + 4194304;
constexpr size_t OF_PBTL = OF_ADF + 4718592;      // ends 108003328 < OF_SJ
// attention K-split partial slots (33KB each): 762 in dead qkv region + 390 in dead omix_bf region
constexpr size_t OF_APART1 = OF_QKV;              // 762 x 8256 f32 = 25.16MB
constexpr size_t OF_APART2 = OF_OMIXB;            // 390 x 8256 f32 = 12.9MB

struct CompJobs { int a[8]; int b[8]; int d[8]; };

// ---------------- f32 -> bf16 convert ----------------
__global__ void k_f2b(const float* __restrict__ src, u16* __restrict__ dst, int n){
  int i = (blockIdx.x * 256 + threadIdx.x) * 4;
  if(i >= n) return;
  f32x4 v = *(const f32x4*)(src + i);
  u32 w0 = (u32)f2bf(v[0]) | ((u32)f2bf(v[1]) << 16);
  u32 w1 = (u32)f2bf(v[2]) | ((u32)f2bf(v[3]) << 16);
  *(u32*)(dst + i) = w0;
  *(u32*)(dst + i + 2) = w1;
}

// ---------------- bf16 NT GEMM: C[M][N] = A[M][K] * B[N][K]^T (m97 structure) ----------------
__global__ __launch_bounds__(256) void k_gemm(const u16* __restrict__ A, const u16* __restrict__ B,
                                              float* __restrict__ C, int K, int N){
  __shared__ u16 aL[128*32];
  __shared__ u16 bL[128*32];
  int bn = blockIdx.x, bm = blockIdx.y;
  int tid = threadIdx.x, lane = tid & 63, w = tid >> 6;
  int wm = w >> 1, wn = w & 1;
  f32x4 acc[4][4] = {};
  int nK = K >> 5;
  const u16* Abase = A + (size_t)bm * 128 * K;
  const u16* Bbase = B + (size_t)bn * 128 * K;
  for(int kt = 0; kt < nK; ++kt){
    __syncthreads();
    #pragma unroll
    for(int t = 0; t < 2; ++t){
      int row = t*64 + w*16 + (lane >> 2);
      int kc = (lane & 3) * 8;
      gload_lds16(Abase + (size_t)row*K + kt*32 + kc, &aL[(t*64 + w*16)*32]);
      gload_lds16(Bbase + (size_t)row*K + kt*32 + kc, &bL[(t*64 + w*16)*32]);
    }
    __syncthreads();
    bf16x8 af[4], bf[4];
    #pragma unroll
    for(int i = 0; i < 4; ++i){
      af[i] = *(const bf16x8*)&aL[(wm*64 + i*16 + (lane & 15))*32 + ((lane >> 4) << 3)];
      bf[i] = *(const bf16x8*)&bL[(wn*64 + i*16 + (lane & 15))*32 + ((lane >> 4) << 3)];
    }
    #pragma unroll
    for(int i = 0; i < 4; ++i)
      #pragma unroll
      for(int j = 0; j < 4; ++j)
        acc[i][j] = MFMA16(af[i], bf[j], acc[i][j]);
  }
  #pragma unroll
  for(int i = 0; i < 4; ++i)
    #pragma unroll
    for(int j = 0; j < 4; ++j)
      #pragma unroll
      for(int r = 0; r < 4; ++r){
        int row = bm*128 + wm*64 + i*16 + ((lane >> 4) << 2) + r;
        int col = bn*128 + wn*64 + j*16 + (lane & 15);
        C[(size_t)row * N + col] = acc[i][j][r];
      }
}

// ---------------- per-row softmax / gate / bf16 casts ----------------
__global__ void k_linprep(const float* __restrict__ qkv, u16* qbf, u16* qlb,
                          u16* kbf, float* klf, u16* klb, float* glf){
  int gtask = blockIdx.x * 4 + (threadIdx.x >> 6);
  int lane = threadIdx.x & 63;
  int n = gtask / 20, t = gtask % 20;
  const float* row = (t < 16) ? (qkv + (size_t)n*3072 + t*128)
                              : (qkv + (size_t)n*3072 + 2048 + (t-16)*128);
  float v0 = row[lane], v1 = row[lane + 64];
  float m = fmaxf(v0, v1);
  #pragma unroll
  for(int o = 1; o < 64; o <<= 1) m = fmaxf(m, __shfl_xor(m, o, 64));
  float e0 = __expf(v0 - m), e1 = __expf(v1 - m);
  float s = e0 + e1;
  #pragma unroll
  for(int o = 1; o < 64; o <<= 1) s += __shfl_xor(s, o, 64);
  float r0 = e0 / s, r1 = e1 / s;
  if(t < 16){
    size_t base = ((size_t)t*2048 + n) * 128;
    qbf[base + lane] = f2bf(v0); qbf[base + 64 + lane] = f2bf(v1);
    qlb[base + lane] = f2bf(r0); qlb[base + 64 + lane] = f2bf(r1);
  } else {
    int g = t - 16;
    size_t base = ((size_t)g*2048 + n) * 128;
    kbf[base + lane] = f2bf(v0); kbf[base + 64 + lane] = f2bf(v1);
    klf[base + lane] = r0;       klf[base + 64 + lane] = r1;
    klb[base + lane] = f2bf(r0); klb[base + 64 + lane] = f2bf(r1);
    float g0 = (fminf(v0, 0.f) - log1pf(__expf(-fabsf(v0)))) * (1.f/16.f);
    float g1 = (fminf(v1, 0.f) - log1pf(__expf(-fabsf(v1)))) * (1.f/16.f);
    glf[base + lane] = g0; glf[base + 64 + lane] = g1;
  }
}

// ---------------- V transpose: vT[g][d][n] = bf16(v[n][d]) ----------------
__global__ __launch_bounds__(256) void k_vt(const float* __restrict__ qkv, u16* __restrict__ vT){
  __shared__ float t[64][65];
  int nt = blockIdx.x, dt = blockIdx.y, g = blockIdx.z;
  int tid = threadIdx.x;
  {
    int r = tid >> 2, c0 = (tid & 3) * 16;
    const float* src = qkv + (size_t)(nt*64 + r)*3072 + 2560 + g*128 + dt*64 + c0;
    #pragma unroll
    for(int q = 0; q < 16; q += 4){
      f32x4 v = *(const f32x4*)(src + q);
      t[r][c0+q] = v[0]; t[r][c0+q+1] = v[1]; t[r][c0+q+2] = v[2]; t[r][c0+q+3] = v[3];
    }
  }
  __syncthreads();
  {
    int d = tid >> 2, c0 = (tid & 3) * 16;
    u16* dst = vT + ((size_t)g*128 + dt*64 + d)*2048 + (size_t)nt*64 + c0;
    #pragma unroll
    for(int half = 0; half < 2; ++half){
      int b = c0 + half*8;
      u32 w0 = (u32)f2bf(t[b+0][d]) | ((u32)f2bf(t[b+1][d]) << 16);
      u32 w1 = (u32)f2bf(t[b+2][d]) | ((u32)f2bf(t[b+3][d]) << 16);
      u32 w2 = (u32)f2bf(t[b+4][d]) | ((u32)f2bf(t[b+5][d]) << 16);
      u32 w3 = (u32)f2bf(t[b+6][d]) | ((u32)f2bf(t[b+7][d]) << 16);
      uint4 o = make_uint4(w0, w1, w2, w3);
      *(uint4*)(dst + half*8) = o;
    }
  }
}

// ---------------- prep1: per distinct chunk (g,c): A = strict(kb kl^T), Tinv by fwd subst ----------------
__global__ __launch_bounds__(256) void k_prep1(const float* __restrict__ klf, const float* __restrict__ glf,
                                               float* __restrict__ tinv){
  __shared__ float KlT[128][68];
  __shared__ float Kb[64][132];
  __shared__ float Am[64][68];
  __shared__ float XT[64][68];
  int idx = blockIdx.x, g = idx >> 5, c = idx & 31, tid = threadIdx.x;
  size_t base = ((size_t)g*2048 + c*64) * 128;
  {
    int r = tid >> 2, d0 = (tid & 3) * 32;
    #pragma unroll
    for(int dd = 0; dd < 32; dd += 4){
      f32x4 kv = *(const f32x4*)(klf + base + r*128 + d0 + dd);
      f32x4 gv = *(const f32x4*)(glf + base + r*128 + d0 + dd);
      KlT[d0+dd][r] = kv[0]; KlT[d0+dd+1][r] = kv[1]; KlT[d0+dd+2][r] = kv[2]; KlT[d0+dd+3][r] = kv[3];
      f32x4 kb = kv * gv;
      *(f32x4*)&Kb[r][d0+dd] = kb;
    }
  }
  __syncthreads();
  {
    int i = tid >> 2, j0 = (tid & 3) * 16;
    f32x4 s[4] = {};
    for(int d = 0; d < 128; ++d){
      float kb = Kb[i][d];
      #pragma unroll
      for(int q = 0; q < 4; ++q){
        f32x4 kl = *(const f32x4*)&KlT[d][j0 + q*4];
        s[q] += kb * kl;
      }
    }
    #pragma unroll
    for(int q = 0; q < 4; ++q) *(f32x4*)&Am[i][j0 + q*4] = s[q];
  }
  __syncthreads();
  if(tid < 64){
    int cc = tid;
    float x0 = (cc == 0) ? 1.f : 0.f;
    XT[cc][0] = x0;
    tinv[(size_t)idx*4096 + cc] = x0;
    for(int i = 1; i < 64; ++i){
      float s = (i == cc) ? 1.f : 0.f;
      int i4 = i & ~3;
      for(int jj = 0; jj < i4; jj += 4){
        f32x4 av = *(const f32x4*)&Am[i][jj];
        f32x4 xv = *(const f32x4*)&XT[cc][jj];
        s -= av[0]*xv[0] + av[1]*xv[1] + av[2]*xv[2] + av[3]*xv[3];
      }
      for(int jj = i4; jj < i; ++jj) s -= Am[i][jj] * XT[cc][jj];
      XT[cc][i] = s;
      tinv[(size_t)idx*4096 + i*64 + cc] = s;
    }
  }
}

// ---------------- prep2a: w = Tinv*kb, u0 = Tinv*vb ----------------
__global__ __launch_bounds__(256) void k_prep2a(const float* __restrict__ klf, const float* __restrict__ glf,
                                                const float* __restrict__ qkv, const float* __restrict__ tinv,
                                                float* __restrict__ wf, u16* __restrict__ wb, float* __restrict__ u0f){
  __shared__ float Ti[64][68];
  __shared__ float B1[64][132]; // kb
  __shared__ float B2[64][132]; // vb
  int idx = blockIdx.x, g = idx >> 5, c = idx & 31, tid = threadIdx.x;
  size_t base = ((size_t)g*2048 + c*64) * 128;
  {
    int r = tid >> 2, d0 = (tid & 3) * 32;
    #pragma unroll
    for(int dd = 0; dd < 32; dd += 4){
      f32x4 kv = *(const f32x4*)(klf + base + r*128 + d0 + dd);
      f32x4 gv = *(const f32x4*)(glf + base + r*128 + d0 + dd);
      f32x4 vv = *(const f32x4*)(qkv + (size_t)(c*64 + r)*3072 + 2560 + g*128 + d0 + dd);
      *(f32x4*)&B1[r][d0+dd] = kv * gv;
      *(f32x4*)&B2[r][d0+dd] = vv * gv;
    }
    int c0 = (tid & 3) * 16;
    #pragma unroll
    for(int q = 0; q < 16; q += 4)
      *(f32x4*)&Ti[r][c0+q] = *(const f32x4*)(tinv + (size_t)idx*4096 + r*64 + c0 + q);
  }
  __syncthreads();
  int i = tid >> 2, cc0 = (tid & 3) * 32;
  f32x4 wa[8] = {}; f32x4 ua[8] = {};
  for(int jj = 0; jj < 64; ++jj){
    float a = Ti[i][jj];
    #pragma unroll
    for(int q = 0; q < 8; ++q){
      f32x4 b1 = *(const f32x4*)&B1[jj][cc0 + q*4];
      f32x4 b2 = *(const f32x4*)&B2[jj][cc0 + q*4];
      wa[q] += a * b1; ua[q] += a * b2;
    }
  }
  #pragma unroll
  for(int q = 0; q < 8; ++q){
    *(f32x4*)(wf + (size_t)idx*8192 + i*128 + cc0 + q*4) = wa[q];
    *(f32x4*)(u0f + (size_t)idx*8192 + i*128 + cc0 + q*4) = ua[q];
    u32 w0 = (u32)f2bf(wa[q][0]) | ((u32)f2bf(wa[q][1]) << 16);
    u32 w1 = (u32)f2bf(wa[q][2]) | ((u32)f2bf(wa[q][3]) << 16);
    u32* dst = (u32*)(wb + (size_t)idx*8192 + i*128 + cc0 + q*4);
    dst[0] = w0; dst[1] = w1;
  }
}

// ---------------- prep2b: D = -(k^T w), BT = (k^T u0)^T; f32 masters + hi/lo mirrors ----------------
__global__ __launch_bounds__(256) void k_prep2b(const float* __restrict__ klf, const float* __restrict__ wf,
                                                const float* __restrict__ u0f,
                                                float* __restrict__ dF, u16* __restrict__ dH, u16* __restrict__ dL,
                                                u16* __restrict__ dTH, u16* __restrict__ dTL,
                                                float* __restrict__ btF, u16* __restrict__ btH, u16* __restrict__ btL){
  __shared__ float Kl[64][132];
  __shared__ float Wm[64][132];
  __shared__ float Um[64][132];
  int idx = blockIdx.x, g = idx >> 5, c = idx & 31, tid = threadIdx.x;
  size_t base = ((size_t)g*2048 + c*64) * 128;
  {
    int r = tid >> 2, d0 = (tid & 3) * 32;
    #pragma unroll
    for(int dd = 0; dd < 32; dd += 4){
      *(f32x4*)&Kl[r][d0+dd] = *(const f32x4*)(klf + base + r*128 + d0 + dd);
      *(f32x4*)&Wm[r][d0+dd] = *(const f32x4*)(wf + (size_t)idx*8192 + r*128 + d0 + dd);
      *(f32x4*)&Um[r][d0+dd] = *(const f32x4*)(u0f + (size_t)idx*8192 + r*128 + d0 + dd);
    }
  }
  __syncthreads();
  int a = tid >> 1, b0 = (tid & 1) * 64;
  f32x4 pa[16] = {}; f32x4 ca[16] = {};
  for(int r = 0; r < 64; ++r){
    float ka = Kl[r][a];
    float ua = Um[r][a];
    #pragma unroll
    for(int q = 0; q < 16; ++q){
      f32x4 wv = *(const f32x4*)&Wm[r][b0 + q*4];
      f32x4 kv = *(const f32x4*)&Kl[r][b0 + q*4];
      pa[q] += ka * wv;
      ca[q] += ua * kv;
    }
  }
  size_t ob = (size_t)idx * 16384;
  #pragma unroll
  for(int q = 0; q < 16; ++q){
    #pragma unroll
    for(int e = 0; e < 4; ++e){
      int b = b0 + q*4 + e;
      float dv = -pa[q][e];
      u16 dh, dl; splitbf(dv, dh, dl);
      dF[ob + a*128 + b] = dv;
      dH[ob + a*128 + b] = dh;
      dL[ob + a*128 + b] = dl;
      dTH[ob + (size_t)b*128 + a] = dh;
      dTL[ob + (size_t)b*128 + a] = dl;
      float cv = ca[q][e];
      u16 ch, cl; splitbf(cv, ch, cl);
      btF[ob + a*128 + b] = cv;
      btH[ob + a*128 + b] = ch;
      btL[ob + a*128 + b] = cl;
    }
  }
}

// ---------------- Kogge-Stone compose round (split-precision) ----------------
__global__ __launch_bounds__(256) void k_ks(
    const float* __restrict__ sDF, const u16* __restrict__ sDH, const u16* __restrict__ sDL,
    const u16* __restrict__ sDTH, const u16* __restrict__ sDTL,
    const float* __restrict__ sBF, const u16* __restrict__ sBH, const u16* __restrict__ sBL,
    float* __restrict__ dDF, u16* __restrict__ dDH, u16* __restrict__ dDL,
    u16* __restrict__ dDTH, u16* __restrict__ dDTL,
    float* __restrict__ dBF, u16* __restrict__ dBH, u16* __restrict__ dBL, int off){
  __shared__ float T[128][132];
  int c = blockIdx.x, g = blockIdx.y, z = blockIdx.z;
  int idx = g*32 + c, tid = threadIdx.x;
  size_t base = (size_t)idx * 16384;
  if(c < off){
    if(z == 0){
      for(int i = tid; i < 4096; i += 256) ((uint4*)(dDF + base))[i] = ((const uint4*)(sDF + base))[i];
      for(int i = tid; i < 2048; i += 256){
        ((uint4*)(dDH + base))[i] = ((const uint4*)(sDH + base))[i];
        ((uint4*)(dDL + base))[i] = ((const uint4*)(sDL + base))[i];
        ((uint4*)(dDTH + base))[i] = ((const uint4*)(sDTH + base))[i];
        ((uint4*)(dDTL + base))[i] = ((const uint4*)(sDTL + base))[i];
      }
    } else {
      for(int i = tid; i < 4096; i += 256) ((uint4*)(dBF + base))[i] = ((const uint4*)(sBF + base))[i];
      for(int i = tid; i < 2048; i += 256){
        ((uint4*)(dBH + base))[i] = ((const uint4*)(sBH + base))[i];
        ((uint4*)(dBL + base))[i] = ((const uint4*)(sBL + base))[i];
      }
    }
    return;
  }
  size_t blo = (size_t)(idx - off) * 16384;
  int lane = tid & 63, w = tid >> 6;
  const u16 *Ah, *Al, *Bh, *Bl;
  if(z == 0){ Ah = sDH + base; Al = sDL + base; Bh = sDTH + blo; Bl = sDTL + blo; }
  else      { Ah = sBH + blo;  Al = sBL + blo;  Bh = sDH + base; Bl = sDL + base; }
  f32x4 acc[2][8] = {};
  #pragma unroll
  for(int ks = 0; ks < 4; ++ks){
    bf16x8 ah[2], al[2], bh[8], bl[8];
    #pragma unroll
    for(int mt = 0; mt < 2; ++mt){
      int ro = (w*32 + mt*16 + (lane & 15))*128 + ks*32 + ((lane >> 4) << 3);
      ah[mt] = *(const bf16x8*)(Ah + ro);
      al[mt] = *(const bf16x8*)(Al + ro);
    }
    #pragma unroll
    for(int nt = 0; nt < 8; ++nt){
      int ro = (nt*16 + (lane & 15))*128 + ks*32 + ((lane >> 4) << 3);
      bh[nt] = *(const bf16x8*)(Bh + ro);
      bl[nt] = *(const bf16x8*)(Bl + ro);
    }
    #pragma unroll
    for(int mt = 0; mt < 2; ++mt)
      #pragma unroll
      for(int nt = 0; nt < 8; ++nt)
        acc[mt][nt] = MFMA16(ah[mt], bh[nt],
                      MFMA16(ah[mt], bl[nt],
                      MFMA16(al[mt], bh[nt], acc[mt][nt])));
  }
  if(z == 0){
    #pragma unroll
    for(int mt = 0; mt < 2; ++mt)
      #pragma unroll
      for(int nt = 0; nt < 8; ++nt)
        #pragma unroll
        for(int r = 0; r < 4; ++r){
          int row = w*32 + mt*16 + ((lane >> 4) << 2) + r;
          int col = nt*16 + (lane & 15);
          float v = acc[mt][nt][r] + sDF[base + row*128 + col] + sDF[blo + row*128 + col];
          dDF[base + row*128 + col] = v;
          u16 hi, lo; splitbf(v, hi, lo);
          dDH[base + row*128 + col] = hi;
          dDL[base + row*128 + col] = lo;
          T[row][col] = v;
        }
    __syncthreads();
    int tcol = tid >> 1, half = tid & 1;
    for(int m = 0; m < 64; ++m){
      float v = T[half*64 + m][tcol];
      u16 hi, lo; splitbf(v, hi, lo);
      dDTH[base + (size_t)tcol*128 + half*64 + m] = hi;
      dDTL[base + (size_t)tcol*128 + half*64 + m] = lo;
    }
  } else {
    #pragma unroll
    for(int mt = 0; mt < 2; ++mt)
      #pragma unroll
      for(int nt = 0; nt < 8; ++nt)
        #pragma unroll
        for(int r = 0; r < 4; ++r){
          int row = w*32 + mt*16 + ((lane >> 4) << 2) + r;
          int col = nt*16 + (lane & 15);
          float v = acc[mt][nt][r] + sBF[base + row*128 + col] + sBF[blo + row*128 + col];
          dBF[base + row*128 + col] = v;
          u16 hi, lo; splitbf(v, hi, lo);
          dBH[base + row*128 + col] = hi;
          dBL[base + row*128 + col] = lo;
        }
  }
}

// ---------------- generic compose: op_d = op_a AFTER op_b ----------------
__global__ __launch_bounds__(256) void k_comp(
    const float* __restrict__ bDF, const u16* __restrict__ bDH, const u16* __restrict__ bDL,
    const u16* __restrict__ bDTH, const u16* __restrict__ bDTL,
    const float* __restrict__ bBTF, const u16* __restrict__ bBTH, const u16* __restrict__ bBTL,
    float* __restrict__ pDF, u16* __restrict__ pDH, u16* __restrict__ pDL,
    u16* __restrict__ pDTH, u16* __restrict__ pDTL,
    float* __restrict__ pBTF, u16* __restrict__ pBTH, u16* __restrict__ pBTL,
    CompJobs jobs){
  __shared__ float T[128][132];
  int job = blockIdx.x, z = blockIdx.y, tid = threadIdx.x;
  int a = jobs.a[job], b = jobs.b[job], d = jobs.d[job] - 128;
  size_t ob = (size_t)d * 16384;
  int lane = tid & 63, w = tid >> 6;
  const u16 *Ah, *Al, *Bh, *Bl;
  const float *F1, *F2;
  if(z == 0){
    Ah = selu(bDH, pDH, a);  Al = selu(bDL, pDL, a);
    Bh = selu(bDTH, pDTH, b); Bl = selu(bDTL, pDTL, b);
    F1 = self32(bDF, pDF, a); F2 = self32(bDF, pDF, b);
  } else {
    Ah = selu(bBTH, pBTH, b); Al = selu(bBTL, pBTL, b);
    Bh = selu(bDH, pDH, a);   Bl = selu(bDL, pDL, a);
    F1 = self32(bBTF, pBTF, a); F2 = self32(bBTF, pBTF, b);
  }
  f32x4 acc[2][8] = {};
  #pragma unroll
  for(int ks = 0; ks < 4; ++ks){
    bf16x8 ah[2], al[2], bh[8], bl[8];
    #pragma unroll
    for(int mt = 0; mt < 2; ++mt){
      int ro = (w*32 + mt*16 + (lane & 15))*128 + ks*32 + ((lane >> 4) << 3);
      ah[mt] = *(const bf16x8*)(Ah + ro);
      al[mt] = *(const bf16x8*)(Al + ro);
    }
    #pragma unroll
    for(int nt = 0; nt < 8; ++nt){
      int ro = (nt*16 + (lane & 15))*128 + ks*32 + ((lane >> 4) << 3);
      bh[nt] = *(const bf16x8*)(Bh + ro);
      bl[nt] = *(const bf16x8*)(Bl + ro);
    }
    #pragma unroll
    for(int mt = 0; mt < 2; ++mt)
      #pragma unroll
      for(int nt = 0; nt < 8; ++nt)
        acc[mt][nt] = MFMA16(ah[mt], bh[nt],
                      MFMA16(ah[mt], bl[nt],
                      MFMA16(al[mt], bh[nt], acc[mt][nt])));
  }
  if(z == 0){
    #pragma unroll
    for(int mt = 0; mt < 2; ++mt)
      #pragma unroll
      for(int nt = 0; nt < 8; ++nt)
        #pragma unroll
        for(int r = 0; r < 4; ++r){
          int row = w*32 + mt*16 + ((lane >> 4) << 2) + r;
          int col = nt*16 + (lane & 15);
          float v = acc[mt][nt][r] + F1[row*128 + col] + F2[row*128 + col];
          pDF[ob + row*128 + col] = v;
          u16 hi, lo; splitbf(v, hi, lo);
          pDH[ob + row*128 + col] = hi;
          pDL[ob + row*128 + col] = lo;
          T[row][col] = v;
        }
    __syncthreads();
    int tcol = tid >> 1, half = tid & 1;
    for(int m = 0; m < 64; ++m){
      float v = T[half*64 + m][tcol];
      u16 hi, lo; splitbf(v, hi, lo);
      pDTH[ob + (size_t)tcol*128 + half*64 + m] = hi;
      pDTL[ob + (size_t)tcol*128 + half*64 + m] = lo;
    }
  } else {
    #pragma unroll
    for(int mt = 0; mt < 2; ++mt)
      #pragma unroll
      for(int nt = 0; nt < 8; ++nt)
        #pragma unroll
        for(int r = 0; r < 4; ++r){
          int row = w*32 + mt*16 + ((lane >> 4) << 2) + r;
          int col = nt*16 + (lane & 15);
          float v = acc[mt][nt][r] + F1[row*128 + col] + F2[row*128 + col];
          pBTF[ob + row*128 + col] = v;
          u16 hi, lo; splitbf(v, hi, lo);
          pBTH[ob + row*128 + col] = hi;
          pBTL[ob + row*128 + col] = lo;
        }
  }
}

// ---------------- head starts (parallel) ----------------
__global__ __launch_bounds__(256) void k_heads(
    const u16* __restrict__ bDH, const u16* __restrict__ bDL,
    const float* __restrict__ bBTF, const u16* __restrict__ bBTH, const u16* __restrict__ bBTL,
    const u16* __restrict__ pDH, const u16* __restrict__ pDL,
    const float* __restrict__ pBTF, const u16* __restrict__ pBTH, const u16* __restrict__ pBTL,
    float* __restrict__ ttF, u16* __restrict__ ttH, u16* __restrict__ ttL, u16* __restrict__ sj){
  int h = blockIdx.x, g = h >> 2, i = h & 3;
  int tid = threadIdx.x, lane = tid & 63, w = tid >> 6;
  int psi = (g == 0) ? -1 : (g == 1 ? 136 : (g == 2 ? 140 : 142));
  int phi = (i == 0) ? -1 : (i == 1 ? g*32 + 31 : (i == 2 ? 128 + g : 132 + g));
  f32x4 acc[2][8] = {};
  if(psi >= 0 && phi >= 0){
    const u16* Ah = selu(bBTH, pBTH, psi);
    const u16* Al = selu(bBTL, pBTL, psi);
    const u16* Bh = selu(bDH, pDH, phi);
    const u16* Bl = selu(bDL, pDL, phi);
    #pragma unroll
    for(int ks = 0; ks < 4; ++ks){
      bf16x8 ah[2], al[2], bh[8], bl[8];
      #pragma unroll
      for(int mt = 0; mt < 2; ++mt){
        int ro = (w*32 + mt*16 + (lane & 15))*128 + ks*32 + ((lane >> 4) << 3);
        ah[mt] = *(const bf16x8*)(Ah + ro);
        al[mt] = *(const bf16x8*)(Al + ro);
      }
      #pragma unroll
      for(int nt = 0; nt < 8; ++nt){
        int ro = (nt*16 + (lane & 15))*128 + ks*32 + ((lane >> 4) << 3);
        bh[nt] = *(const bf16x8*)(Bh + ro);
        bl[nt] = *(const bf16x8*)(Bl + ro);
      }
      #pragma unroll
      for(int mt = 0; mt < 2; ++mt)
        #pragma unroll
        for(int nt = 0; nt < 8; ++nt)
          acc[mt][nt] = MFMA16(ah[mt], bh[nt],
                        MFMA16(ah[mt], bl[nt],
                        MFMA16(al[mt], bh[nt], acc[mt][nt])));
    }
  }
  const float* Pf = (psi >= 0) ? self32(bBTF, pBTF, psi) : nullptr;
  const float* Ff = (phi >= 0) ? self32(bBTF, pBTF, phi) : nullptr;
  #pragma unroll
  for(int mt = 0; mt < 2; ++mt)
    #pragma unroll
    for(int nt = 0; nt < 8; ++nt)
      #pragma unroll
      for(int r = 0; r < 4; ++r){
        int row = w*32 + mt*16 + ((lane >> 4) << 2) + r;
        int col = nt*16 + (lane & 15);
        float v = acc[mt][nt][r];
        if(Pf) v += Pf[row*128 + col];
        if(Ff) v += Ff[row*128 + col];
        u16 hi, lo; splitbf(v, hi, lo);
        size_t o = (size_t)h*16384 + row*128 + col;
        ttF[o] = v; ttH[o] = hi; ttL[o] = lo;
        sj[(size_t)(h*32)*16384 + row*128 + col] = hi;
      }
}

// ---------------- expand: ST_{h,c} = TT_h + nt(TT_h, Dg_{c-1}) + BTg_{c-1} ----------------
__global__ __launch_bounds__(256) void k_expand(const u16* __restrict__ bDH, const u16* __restrict__ bDL,
                                                const float* __restrict__ bBF, const float* __restrict__ ttF,
                                                const u16* __restrict__ ttH, const u16* __restrict__ ttL,
                                                u16* __restrict__ sj){
  int j = blockIdx.x;
  int c = j & 31;
  if(c == 0) return;
  int h = j >> 5, g = h >> 2;
  size_t obase = (size_t)j * 16384;
  size_t mb = (size_t)(g*32 + c - 1) * 16384;
  size_t tb = (size_t)h * 16384;
  int tid = threadIdx.x, lane = tid & 63, w = tid >> 6;
  f32x4 acc[2][8] = {};
  #pragma unroll
  for(int ks = 0; ks < 4; ++ks){
    bf16x8 ah[2], al[2], bh[8], bl[8];
    #pragma unroll
    for(int mt = 0; mt < 2; ++mt){
      int ro = (w*32 + mt*16 + (lane & 15))*128 + ks*32 + ((lane >> 4) << 3);
      ah[mt] = *(const bf16x8*)(ttH + tb + ro);
      al[mt] = *(const bf16x8*)(ttL + tb + ro);
    }
    #pragma unroll
    for(int nt = 0; nt < 8; ++nt){
      int ro = (nt*16 + (lane & 15))*128 + ks*32 + ((lane >> 4) << 3);
      bh[nt] = *(const bf16x8*)(bDH + mb + ro);
      bl[nt] = *(const bf16x8*)(bDL + mb + ro);
    }
    #pragma unroll
    for(int mt = 0; mt < 2; ++mt)
      #pragma unroll
      for(int nt = 0; nt < 8; ++nt)
        acc[mt][nt] = MFMA16(ah[mt], bh[nt],
                      MFMA16(ah[mt], bl[nt],
                      MFMA16(al[mt], bh[nt], acc[mt][nt])));
  }
  #pragma unroll
  for(int mt = 0; mt < 2; ++mt)
    #pragma unroll
    for(int nt = 0; nt < 8; ++nt)
      #pragma unroll
      for(int r = 0; r < 4; ++r){
        int row = w*32 + mt*16 + ((lane >> 4) << 2) + r;
        int col = nt*16 + (lane & 15);
        float v = acc[mt][nt][r] + ttF[tb + row*128 + col] + bBF[mb + row*128 + col];
        sj[obase + row*128 + col] = f2bf(v);
      }
}

// ---------------- o_lin per (h,c): o = q@S + tril(q k^T)@(u0 - w@S); omix = 0.5*o ----------------
__global__ __launch_bounds__(256) void k_olin(const u16* __restrict__ qlb, const u16* __restrict__ klb,
                                              const u16* __restrict__ wb, const float* __restrict__ u0f,
                                              const u16* __restrict__ sj, float* __restrict__ omix){
  __shared__ u16 ut[128*64];    // u_i^T [d][kv], swizzled
  __shared__ u16 pl[4][16*64];  // per-wave masked scores, swizzled
  int j = blockIdx.x;
  int h = j >> 5, c = j & 31, g = h >> 2, idx = g*32 + c;
  int tid = threadIdx.x, lane = tid & 63, w = tid >> 6;
  const u16* Sj = sj + (size_t)j * 16384;
  const u16* Q  = qlb + ((size_t)h*2048 + c*64) * 128;
  const u16* Kc = klb + ((size_t)g*2048 + c*64) * 128;
  const u16* W  = wb + (size_t)idx * 8192;
  const float* U0 = u0f + (size_t)idx * 8192;
  bf16x8 aq[4], aw[4];
  #pragma unroll
  for(int ks = 0; ks < 4; ++ks){
    aq[ks] = *(const bf16x8*)(Q + (w*16 + (lane & 15))*128 + ks*32 + ((lane >> 4) << 3));
    aw[ks] = *(const bf16x8*)(W + (w*16 + (lane & 15))*128 + ks*32 + ((lane >> 4) << 3));
  }
  f32x4 t1[8] = {}, ui[8] = {};
  #pragma unroll
  for(int ks = 0; ks < 4; ++ks)
    #pragma unroll
    for(int nt = 0; nt < 8; ++nt){
      bf16x8 b = *(const bf16x8*)(Sj + (nt*16 + (lane & 15))*128 + ks*32 + ((lane >> 4) << 3));
      t1[nt] = MFMA16(aq[ks], b, t1[nt]);
      ui[nt] = MFMA16(aw[ks], b, ui[nt]);
    }
  f32x4 sc[4] = {};
  #pragma unroll
  for(int ks = 0; ks < 4; ++ks)
    #pragma unroll
    for(int nt = 0; nt < 4; ++nt){
      bf16x8 b = *(const bf16x8*)(Kc + (nt*16 + (lane & 15))*128 + ks*32 + ((lane >> 4) << 3));
      sc[nt] = MFMA16(aq[ks], b, sc[nt]);
    }
  // masked scores to per-wave LDS
  #pragma unroll
  for(int nt = 0; nt < 4; ++nt)
    #pragma unroll
    for(int r = 0; r < 4; ++r){
      int row = ((lane >> 4) << 2) + r;
      int col = nt*16 + (lane & 15);
      int grow = w*16 + row;
      float v = (col <= grow) ? sc[nt][r] : 0.f;
      int bo = (row*128 + col*2) ^ ((row & 7) << 4);
      *(u16*)((char*)&pl[w][0] + bo) = f2bf(v);
    }
  // u_i = u0 - w@S, transposed into LDS
  #pragma unroll
  for(int nt = 0; nt < 8; ++nt)
    #pragma unroll
    for(int r = 0; r < 4; ++r){
      int kv = w*16 + ((lane >> 4) << 2) + r;
      int d  = nt*16 + (lane & 15);
      float v = U0[kv*128 + d] - ui[nt][r];
      int bo = (d*128 + kv*2) ^ ((d & 7) << 4);
      *(u16*)((char*)ut + bo) = f2bf(v);
    }
  __syncthreads();
  f32x4 o2[8] = {};
  #pragma unroll
  for(int ks2 = 0; ks2 < 2; ++ks2){
    int row = lane & 15;
    int boA = (row*128 + ks2*64 + ((lane >> 4) << 4)) ^ ((row & 7) << 4);
    bf16x8 a = *(const bf16x8*)((const char*)&pl[w][0] + boA);
    #pragma unroll
    for(int nt = 0; nt < 8; ++nt){
      int d = nt*16 + (lane & 15);
      int boB = (d*128 + ks2*64 + ((lane >> 4) << 4)) ^ ((d & 7) << 4);
      bf16x8 b = *(const bf16x8*)((const char*)ut + boB);
      o2[nt] = MFMA16(a, b, o2[nt]);
    }
  }
  #pragma unroll
  for(int nt = 0; nt < 8; ++nt)
    #pragma unroll
    for(int r = 0; r < 4; ++r){
      int grow = c*64 + w*16 + ((lane >> 4) << 2) + r;
      int d = nt*16 + (lane & 15);
      omix[(size_t)grow*2048 + h*128 + d] = 0.5f * (t1[nt][r] + o2[nt][r]);
    }
}

// ---------------- base causal attention: uniform 16-kt segments, unnormalized exp ----------------
// bid<128: (h, qb<8) single segment -> finalize into omix.
// bid>=128: slot = bid-128 = h*72 + j; j -> (qb>=8, seg); store partial (acc f32 + lsum) in slot.
__global__ __launch_bounds__(256) void k_attn(const u16* __restrict__ qbf, const u16* __restrict__ kbf,
                                              const u16* __restrict__ vT, float* __restrict__ omix,
                                              float* __restrict__ part1, float* __restrict__ part2){
  __shared__ u16 pl[4][640]; // per-wave P: [16 rows][80B stride]
  int bid = blockIdx.x;
  int h, qb, kt0, kt1, slot = -1;
  if(bid < 128){ h = bid >> 3; qb = bid & 7; kt0 = 0; kt1 = 2*(qb+1); }
  else {
    int t = bid - 128; h = t / 72; int j = t % 72;
    int seg;
    if(j < 16){ qb = 8 + (j >> 1); seg = j & 1; }
    else if(j < 40){ int q = j - 16; qb = 16 + q/3; seg = q - (qb-16)*3; }
    else { int q = j - 40; qb = 24 + (q >> 2); seg = q & 3; }
    slot = t;
    kt0 = seg*16;
    int nt2 = 2*(qb+1);
    kt1 = (kt0 + 16 < nt2) ? kt0 + 16 : nt2;
  }
  int g = h >> 2;
  int tid = threadIdx.x, lane = tid & 63, w = tid >> 6;
  const u16* Q = qbf + ((size_t)h*2048 + qb*64 + w*16) * 128;
  const u16* K = kbf + (size_t)g*2048*128;
  const u16* V = vT + (size_t)g*128*2048;
  bf16x8 aq[4];
  #pragma unroll
  for(int ks = 0; ks < 4; ++ks)
    aq[ks] = *(const bf16x8*)(Q + (lane & 15)*128 + ks*32 + ((lane >> 4) << 3));
  f32x4 acc[8] = {};
  float lsum[4] = {0.f, 0.f, 0.f, 0.f};
  const float scale = 0.08838834764831845f;
  int qrow0 = qb*64 + w*16 + ((lane >> 4) << 2);
  for(int kt = kt0; kt < kt1; ++kt){
    f32x4 s[2];
    #pragma unroll
    for(int ct = 0; ct < 2; ++ct){
      f32x4 t = {};
      #pragma unroll
      for(int ks = 0; ks < 4; ++ks){
        bf16x8 b = *(const bf16x8*)(K + (size_t)(kt*32 + ct*16 + (lane & 15))*128 + ks*32 + ((lane >> 4) << 3));
        t = MFMA16(aq[ks], b, t);
      }
      s[ct] = t;
    }
    // unnormalized p = exp(s*scale) with causal mask; scores are O(+-5) -> no overflow
    #pragma unroll
    for(int ct = 0; ct < 2; ++ct)
      #pragma unroll
      for(int r = 0; r < 4; ++r){
        int col = kt*32 + ct*16 + (lane & 15);
        float p = (col <= qrow0 + r) ? __expf(s[ct][r] * scale) : 0.f;
        s[ct][r] = p;
      }
    #pragma unroll
    for(int r = 0; r < 4; ++r) lsum[r] += s[0][r] + s[1][r];
    #pragma unroll
    for(int ct = 0; ct < 2; ++ct)
      #pragma unroll
      for(int r = 0; r < 4; ++r){
        int row = ((lane >> 4) << 2) + r;
        int col = ct*16 + (lane & 15);
        *(u16*)((char*)&pl[w][0] + row*80 + col*2) = f2bf(s[ct][r]);
      }
    int prow = lane & 15;
    bf16x8 ap = *(const bf16x8*)((const char*)&pl[w][0] + prow*80 + ((lane >> 4) << 4));
    #pragma unroll
    for(int nt = 0; nt < 8; ++nt){
      bf16x8 b = *(const bf16x8*)(V + (size_t)(nt*16 + (lane & 15))*2048 + kt*32 + ((lane >> 4) << 3));
      acc[nt] = MFMA16(ap, b, acc[nt]);
    }
  }
  // one final 16-lane reduction of the row-sums
  #pragma unroll
  for(int r = 0; r < 4; ++r){
    lsum[r] += __shfl_xor(lsum[r], 1, 64);
    lsum[r] += __shfl_xor(lsum[r], 2, 64);
    lsum[r] += __shfl_xor(lsum[r], 4, 64);
    lsum[r] += __shfl_xor(lsum[r], 8, 64);
  }
  if(slot < 0){
    #pragma unroll
    for(int nt = 0; nt < 8; ++nt)
      #pragma unroll
      for(int r = 0; r < 4; ++r){
        int row = qb*64 + w*16 + ((lane >> 4) << 2) + r;
        int d = nt*16 + (lane & 15);
        size_t o = (size_t)row*2048 + h*128 + d;
        omix[o] += 0.5f * acc[nt][r] / lsum[r];
      }
  } else {
    float* P = slotp(part1, part2, slot);
    #pragma unroll
    for(int nt = 0; nt < 8; ++nt)
      #pragma unroll
      for(int r = 0; r < 4; ++r){
        int row = w*16 + ((lane >> 4) << 2) + r;
        int d = nt*16 + (lane & 15);
        P[(size_t)row*128 + d] = acc[nt][r];
      }
    if((lane & 15) == 0)
      #pragma unroll
      for(int r = 0; r < 4; ++r)
        P[8192 + w*16 + ((lane >> 4) << 2) + r] = lsum[r];
  }
}

// ---------------- combine attention K-segments (2..4): omix += 0.5*sum(acc)/sum(l) ----------------
__global__ __launch_bounds__(256) void k_acomb(const float* __restrict__ part1, const float* __restrict__ part2,
                                               float* __restrict__ omix){
  int bid = blockIdx.x;             // h*24 + (qb-8)
  int h = bid / 24, qx = bid % 24, qb = 8 + qx;
  int nseg = (qb >= 24) ? 4 : (qb >= 16) ? 3 : 2;
  int off = (qb < 16) ? (qb-8)*2 : (qb < 24) ? 16 + (qb-16)*3 : 40 + (qb-24)*4;
  int s0 = h*72 + off;
  int tid = threadIdx.x;
  #pragma unroll
  for(int it = 0; it < 8; ++it){
    int i = it*1024 + tid*4;
    int row = i >> 7;
    f32x4 a = {};
    float l = 0.f;
    for(int s = 0; s < nseg; ++s){
      const float* P = slotpc(part1, part2, s0 + s);
      a += *(const f32x4*)(P + i);
      l += P[8192 + row];
    }
    float* dst = omix + (size_t)(qb*64 + row)*2048 + h*128 + (i & 127);
    f32x4 cur = *(const f32x4*)dst;
    *(f32x4*)dst = cur + a * (0.5f / l);
  }
}

// ---------------- launch ----------------
extern "C" void kernel_launch(void* const* d_in, const int* in_sizes, int n_in,
                              void* d_out, int out_size, void* d_ws, size_t ws_size,
                              hipStream_t stream){
  (void)in_sizes; (void)n_in; (void)out_size; (void)ws_size;
  const float* hs = (const float*)d_in[0];
  const float* Wq = (const float*)d_in[1];
  const float* Wk = (const float*)d_in[2];
  const float* Wv = (const float*)d_in[3];
  const float* Wo = (const float*)d_in[4];
  float* out = (float*)d_out;
  char* ws = (char*)d_ws;

  u16*   hs_bf   = (u16*)(ws + OF_HSBF);
  u16*   wqkv_bf = (u16*)(ws + OF_WQKVBF);
  u16*   wo_bf   = (u16*)(ws + OF_WOBF);
  float* qkv     = (float*)(ws + OF_QKV);
  u16*   qbf     = (u16*)(ws + OF_QBF);
  u16*   kbf     = (u16*)(ws + OF_KBF);
  u16*   vT      = (u16*)(ws + OF_VT);
  u16*   qlb     = (u16*)(ws + OF_QLB);
  float* klf     = (float*)(ws + OF_KLF);
  u16*   klb     = (u16*)(ws + OF_KLB);
  float* glf     = (float*)(ws + OF_GLF);
  float* tinvb   = (float*)(ws + OF_TINV);
  float* wf      = (float*)(ws + OF_WF);
  u16*   wb      = (u16*)(ws + OF_WB);
  float* u0f     = (float*)(ws + OF_U0);
  u16*   sjb     = (u16*)(ws + OF_SJ);
  float* omix    = (float*)(ws + OF_OMIX);
  u16*   omix_bf = (u16*)(ws + OF_OMIXB);
  // scan buffers
  float* aDF  = (float*)(ws + OF_ADF);
  u16*   aDH  = (u16*)(ws + OF_ADH);
  u16*   aDL  = (u16*)(ws + OF_ADL);
  u16*   aDTH = (u16*)(ws + OF_ADTH);
  u16*   aDTL = (u16*)(ws + OF_ADTL);
  float* aBTF = (float*)(ws + OF_ABTF);
  u16*   aBTH = (u16*)(ws + OF_ABTH);
  u16*   aBTL = (u16*)(ws + OF_ABTL);
  float* bDF  = (float*)(ws + OF_BDF);
  u16*   bDH  = (u16*)(ws + OF_BDH);
  u16*   bDL  = (u16*)(ws + OF_BDL);
  u16*   bDTH = (u16*)(ws + OF_BDTH);
  u16*   bDTL = (u16*)(ws + OF_BDTL);
  float* bBTF = (float*)(ws + OF_BBTF);
  u16*   bBTH = (u16*)(ws + OF_BBTH);
  u16*   bBTL = (u16*)(ws + OF_BBTL);
  float* ttF  = (float*)(ws + OF_TTF);
  u16*   ttH  = (u16*)(ws + OF_TTH);
  u16*   ttL  = (u16*)(ws + OF_TTL);
  // op pool
  float* pDF  = (float*)(ws + OF_PDF);
  float* pBTF = (float*)(ws + OF_PBTF);
  u16*   pDH  = (u16*)(ws + OF_PDH);
  u16*   pDL  = (u16*)(ws + OF_PDL);
  u16*   pDTH = (u16*)(ws + OF_PDTH);
  u16*   pDTL = (u16*)(ws + OF_PDTL);
  u16*   pBTH = (u16*)(ws + OF_PBTH);
  u16*   pBTL = (u16*)(ws + OF_PBTL);
  float* apart1 = (float*)(ws + OF_APART1);
  float* apart2 = (float*)(ws + OF_APART2);

  k_f2b<<<4096, 256, 0, stream>>>(hs, hs_bf, 4194304);
  k_f2b<<<4096, 256, 0, stream>>>(Wq, wqkv_bf, 4194304);
  k_f2b<<<1024, 256, 0, stream>>>(Wk, wqkv_bf + 2048*2048, 1048576);
  k_f2b<<<1024, 256, 0, stream>>>(Wv, wqkv_bf + 2560*2048, 1048576);
  k_f2b<<<4096, 256, 0, stream>>>(Wo, wo_bf, 4194304);

  k_gemm<<<dim3(24, 16), 256, 0, stream>>>(hs_bf, wqkv_bf, qkv, 2048, 3072);
  k_linprep<<<10240, 256, 0, stream>>>(qkv, qbf, qlb, kbf, klf, klb, glf);
  k_vt<<<dim3(32, 2, 4), 256, 0, stream>>>(qkv, vT);

  k_prep1<<<128, 256, 0, stream>>>(klf, glf, tinvb);
  k_prep2a<<<128, 256, 0, stream>>>(klf, glf, qkv, tinvb, wf, wb, u0f);
  k_prep2b<<<128, 256, 0, stream>>>(klf, wf, u0f, aDF, aDH, aDL, aDTH, aDTL, aBTF, aBTH, aBTL);

  // Kogge-Stone prefix-compose within groups (5 rounds, ping-pong; result in side B)
  k_ks<<<dim3(32, 4, 2), 256, 0, stream>>>(aDF, aDH, aDL, aDTH, aDTL, aBTF, aBTH, aBTL,
                                           bDF, bDH, bDL, bDTH, bDTL, bBTF, bBTH, bBTL, 1);
  k_ks<<<dim3(32, 4, 2), 256, 0, stream>>>(bDF, bDH, bDL, bDTH, bDTL, bBTF, bBTH, bBTL,
                                           aDF, aDH, aDL, aDTH, aDTL, aBTF, aBTH, aBTL, 2);
  k_ks<<<dim3(32, 4, 2), 256, 0, stream>>>(aDF, aDH, aDL, aDTH, aDTL, aBTF, aBTH, aBTL,
                                           bDF, bDH, bDL, bDTH, bDTL, bBTF, bBTH, bBTL, 4);
  k_ks<<<dim3(32, 4, 2), 256, 0, stream>>>(bDF, bDH, bDL, bDTH, bDTL, bBTF, bBTH, bBTL,
                                           aDF, aDH, aDL, aDTH, aDTL, aBTF, aBTH, aBTL, 8);
  k_ks<<<dim3(32, 4, 2), 256, 0, stream>>>(aDF, aDH, aDL, aDTH, aDTL, aBTF, aBTH, aBTL,
                                           bDF, bDH, bDL, bDTH, bDTL, bBTF, bBTH, bBTL, 16);

  // group-operator powers + group-level prefix (pool slots; op_d = op_a AFTER op_b)
  CompJobs j1{}; // Phi_g^2
  for(int g = 0; g < 4; ++g){ j1.a[g] = g*32+31; j1.b[g] = g*32+31; j1.d[g] = 128+g; }
  k_comp<<<dim3(4, 2), 256, 0, stream>>>(bDF, bDH, bDL, bDTH, bDTL, bBTF, bBTH, bBTL,
                                         pDF, pDH, pDL, pDTH, pDTL, pBTF, pBTH, pBTL, j1);
  CompJobs j2{}; // Phi^3, Phi^4
  for(int g = 0; g < 4; ++g){
    j2.a[g]   = 128+g; j2.b[g]   = g*32+31; j2.d[g]   = 132+g;
    j2.a[4+g] = 128+g; j2.b[4+g] = 128+g;   j2.d[4+g] = 136+g;
  }
  k_comp<<<dim3(8, 2), 256, 0, stream>>>(bDF, bDH, bDL, bDTH, bDTL, bBTF, bBTH, bBTL,
                                         pDF, pDH, pDL, pDTH, pDTL, pBTF, pBTH, pBTL, j2);
  CompJobs j3{}; // Psi2; T
  j3.a[0] = 137; j3.b[0] = 136; j3.d[0] = 140;
  j3.a[1] = 138; j3.b[1] = 137; j3.d[1] = 141;
  k_comp<<<dim3(2, 2), 256, 0, stream>>>(bDF, bDH, bDL, bDTH, bDTL, bBTF, bBTH, bBTL,
                                         pDF, pDH, pDL, pDTH, pDTL, pBTF, pBTH, pBTL, j3);
  CompJobs j4{}; // Psi3
  j4.a[0] = 141; j4.b[0] = 136; j4.d[0] = 142;
  k_comp<<<dim3(1, 2), 256, 0, stream>>>(bDF, bDH, bDL, bDTH, bDTL, bBTF, bBTH, bBTL,
                                         pDF, pDH, pDL, pDTH, pDTL, pBTF, pBTH, pBTL, j4);

  k_heads<<<16, 256, 0, stream>>>(bDH, bDL, bBTF, bBTH, bBTL,
                                  pDH, pDL, pBTF, pBTH, pBTL, ttF, ttH, ttL, sjb);
  k_expand<<<512, 256, 0, stream>>>(bDH, bDL, bBTF, ttF, ttH, ttL, sjb);

  k_olin<<<512, 256, 0, stream>>>(qlb, klb, wb, u0f, sjb, omix);
  k_attn<<<1280, 256, 0, stream>>>(qbf, kbf, vT, omix, apart1, apart2);
  k_acomb<<<384, 256, 0, stream>>>(apart1, apart2, omix);

  k_f2b<<<4096, 256, 0, stream>>>(omix, omix_bf, 4194304);
  k_gemm<<<dim3(16, 16), 256, 0, stream>>>(omix_bf, wo_bf, out, 2048, 2048);
}

// Round 7
// 758.391 us; speedup vs baseline: 1.0649x; 1.0649x over previous
//
#include <hip/hip_runtime.h>
#include <hip/hip_bf16.h>

typedef unsigned short u16;
typedef unsigned int u32;
typedef __bf16 bf16x8 __attribute__((ext_vector_type(8)));
typedef float f32x4 __attribute__((ext_vector_type(4)));

#define MFMA16(a,b,c) __builtin_amdgcn_mfma_f32_16x16x32_bf16((a),(b),(c),0,0,0)

__device__ __forceinline__ u16 f2bf(float f){
  u32 u = __builtin_bit_cast(u32, f);
  u32 r = (u + 0x7fffu + ((u >> 16) & 1u)) >> 16;
  return (u16)r;
}
__device__ __forceinline__ float bf2f(u16 h){
  u32 u = ((u32)h) << 16;
  return __builtin_bit_cast(float, u);
}
__device__ __forceinline__ void splitbf(float x, u16& hi, u16& lo){
  hi = f2bf(x);
  lo = f2bf(x - bf2f(hi));
}
__device__ __forceinline__ void gload_lds16(const u16* g, u16* l){
  __builtin_amdgcn_global_load_lds((__attribute__((address_space(1))) void*)(g),
                                   (__attribute__((address_space(3))) void*)(l), 16, 0, 0);
}
__device__ __forceinline__ const u16* selu(const u16* barr, const u16* parr, int i){
  return (i < 128) ? (barr + (size_t)i*16384) : (parr + (size_t)(i-128)*16384);
}
__device__ __forceinline__ const float* self32(const float* barr, const float* parr, int i){
  return (i < 128) ? (barr + (size_t)i*16384) : (parr + (size_t)(i-128)*16384);
}
// attention partial slots: 16512 f32 each (128x128 acc + 128 lsum)
__device__ __forceinline__ float* slotp(float* p1, float* p2, int s){
  return (s < 381) ? (p1 + (size_t)s*16512) : (p2 + (size_t)(s-381)*16512);
}
__device__ __forceinline__ const float* slotpc(const float* p1, const float* p2, int s){
  return (s < 381) ? (p1 + (size_t)s*16512) : (p2 + (size_t)(s-381)*16512);
}

// ---------------- workspace layout (bytes) ----------------
constexpr size_t OF_HSBF   = 0;           // hs bf16 [2048][2048] (dead after gemm1)
constexpr size_t OF_WQKVBF = 8388608;     // Wqkv bf16 [3072][2048] (dead after gemm1)
constexpr size_t OF_WOBF   = 20971520;    // Wo bf16 [2048][2048]
constexpr size_t OF_QKV    = 29360128;    // qkv f32 [2048][3072] (dead after prep2a/vt)
constexpr size_t OF_QBF    = 54525952;    // raw q bf16 [16][2048][128]
constexpr size_t OF_KBF    = 62914560;    // raw k bf16 [4][2048][128]
constexpr size_t OF_VT     = 65011712;    // vT bf16 [4][128][2048]
constexpr size_t OF_QLB    = 67108864;    // softmax q bf16 [16][2048][128]
constexpr size_t OF_KLF    = 75497472;    // softmax k f32 [4][2048][128] (dead after prep2b)
constexpr size_t OF_KLB    = 79691776;    // softmax k bf16
constexpr size_t OF_GLF    = 81788928;    // gate f32 (dead after prep2a)
constexpr size_t OF_TINV   = 85983232;    // Tinv f32 (dead after prep2a)
constexpr size_t OF_WF     = 88080384;    // w f32 (dead after prep2b)
constexpr size_t OF_WB     = 92274688;    // w bf16
constexpr size_t OF_U0     = 94371840;    // u0 f32 [128][64][128]
constexpr size_t OF_SJ     = 111149056;   // S^T states bf16 [512][128][128]
constexpr size_t OF_OMIX   = 127926272;   // f32 [2048][2048] (written by olin, after scan)
constexpr size_t OF_OMIXB  = 144703488;   // bf16 [2048][2048] (written at end)
// scan operator buffers (D = M - I, f32 master + hi/lo bf16 mirrors; BT f32 + hi/lo):
// side A (written by prep2b, rounds 2,4):
constexpr size_t OF_ADF  = 102760448;             // D f32 8MB
constexpr size_t OF_ABTF = OF_OMIX;               // BT f32 8MB (omix dead until olin)
constexpr size_t OF_ADH  = OF_OMIX + 8388608;     // D hi 4MB
constexpr size_t OF_ADL  = OF_OMIX + 12582912;    // D lo 4MB
constexpr size_t OF_ADTH = OF_OMIXB;              // D^T hi 4MB
constexpr size_t OF_ADTL = OF_OMIXB + 4194304;    // D^T lo 4MB
constexpr size_t OF_ABTH = OF_KLF;                // BT hi 4MB
constexpr size_t OF_ABTL = OF_GLF;                // BT lo 4MB
// side B (written by rounds 1,3,5; read by comp/heads/expand):
constexpr size_t OF_BDF  = OF_QKV;                // 8MB
constexpr size_t OF_BBTF = OF_QKV + 8388608;      // 8MB
constexpr size_t OF_BDH  = OF_QKV + 16777216;     // 4MB
constexpr size_t OF_BDL  = OF_QKV + 20971520;     // 4MB (ends at OF_QBF)
constexpr size_t OF_BDTH = OF_HSBF;               // 4MB
constexpr size_t OF_BDTL = OF_HSBF + 4194304;     // 4MB
constexpr size_t OF_BBTH = OF_WQKVBF;             // 4MB
constexpr size_t OF_BBTL = OF_WQKVBF + 4194304;   // 4MB
// head-start states TT_h (16 x 128x128): f32 + hi/lo mirrors
constexpr size_t OF_TTF  = OF_TINV;               // 1MB
constexpr size_t OF_TTH  = OF_WQKVBF + 8388608;   // 512KB
constexpr size_t OF_TTL  = OF_WQKVBF + 8912896;   // 512KB
// op pool (16 slots: powers + group prefixes), overlaid on dead side-A DF region:
constexpr size_t OF_PDF  = OF_ADF;                // 1MB (16 x 64KB)
constexpr size_t OF_PBTF = OF_ADF + 1048576;      // 1MB
constexpr size_t OF_PDH  = OF_ADF + 2097152;      // 512KB
constexpr size_t OF_PDL  = OF_ADF + 2621440;
constexpr size_t OF_PDTH = OF_ADF + 3145728;
constexpr size_t OF_PDTL = OF_ADF + 3670016;
constexpr size_t OF_PBTH = OF_ADF + 4194304;
constexpr size_t OF_PBTL = OF_ADF + 4718592;      // ends 108003328 < OF_SJ
// attention K-split partial slots (66KB each): 381 in dead qkv region + 195 at omix_bf region
constexpr size_t OF_APART1 = OF_QKV;              // 381 x 16512 f32 = 25.16MB
constexpr size_t OF_APART2 = OF_OMIXB;            // 195 x 16512 f32 = 12.88MB (proven footprint)

struct CompJobs { int a[8]; int b[8]; int d[8]; };

// ---------------- f32 -> bf16 convert ----------------
__global__ void k_f2b(const float* __restrict__ src, u16* __restrict__ dst, int n){
  int i = (blockIdx.x * 256 + threadIdx.x) * 4;
  if(i >= n) return;
  f32x4 v = *(const f32x4*)(src + i);
  u32 w0 = (u32)f2bf(v[0]) | ((u32)f2bf(v[1]) << 16);
  u32 w1 = (u32)f2bf(v[2]) | ((u32)f2bf(v[3]) << 16);
  *(u32*)(dst + i) = w0;
  *(u32*)(dst + i + 2) = w1;
}

// ---------------- bf16 NT GEMM: C[M][N] = A[M][K] * B[N][K]^T (m97 structure) ----------------
__global__ __launch_bounds__(256) void k_gemm(const u16* __restrict__ A, const u16* __restrict__ B,
                                              float* __restrict__ C, int K, int N){
  __shared__ u16 aL[128*32];
  __shared__ u16 bL[128*32];
  int bn = blockIdx.x, bm = blockIdx.y;
  int tid = threadIdx.x, lane = tid & 63, w = tid >> 6;
  int wm = w >> 1, wn = w & 1;
  f32x4 acc[4][4] = {};
  int nK = K >> 5;
  const u16* Abase = A + (size_t)bm * 128 * K;
  const u16* Bbase = B + (size_t)bn * 128 * K;
  for(int kt = 0; kt < nK; ++kt){
    __syncthreads();
    #pragma unroll
    for(int t = 0; t < 2; ++t){
      int row = t*64 + w*16 + (lane >> 2);
      int kc = (lane & 3) * 8;
      gload_lds16(Abase + (size_t)row*K + kt*32 + kc, &aL[(t*64 + w*16)*32]);
      gload_lds16(Bbase + (size_t)row*K + kt*32 + kc, &bL[(t*64 + w*16)*32]);
    }
    __syncthreads();
    bf16x8 af[4], bf[4];
    #pragma unroll
    for(int i = 0; i < 4; ++i){
      af[i] = *(const bf16x8*)&aL[(wm*64 + i*16 + (lane & 15))*32 + ((lane >> 4) << 3)];
      bf[i] = *(const bf16x8*)&bL[(wn*64 + i*16 + (lane & 15))*32 + ((lane >> 4) << 3)];
    }
    #pragma unroll
    for(int i = 0; i < 4; ++i)
      #pragma unroll
      for(int j = 0; j < 4; ++j)
        acc[i][j] = MFMA16(af[i], bf[j], acc[i][j]);
  }
  #pragma unroll
  for(int i = 0; i < 4; ++i)
    #pragma unroll
    for(int j = 0; j < 4; ++j)
      #pragma unroll
      for(int r = 0; r < 4; ++r){
        int row = bm*128 + wm*64 + i*16 + ((lane >> 4) << 2) + r;
        int col = bn*128 + wn*64 + j*16 + (lane & 15);
        C[(size_t)row * N + col] = acc[i][j][r];
      }
}

// ---------------- per-row softmax / gate / bf16 casts ----------------
__global__ void k_linprep(const float* __restrict__ qkv, u16* qbf, u16* qlb,
                          u16* kbf, float* klf, u16* klb, float* glf){
  int gtask = blockIdx.x * 4 + (threadIdx.x >> 6);
  int lane = threadIdx.x & 63;
  int n = gtask / 20, t = gtask % 20;
  const float* row = (t < 16) ? (qkv + (size_t)n*3072 + t*128)
                              : (qkv + (size_t)n*3072 + 2048 + (t-16)*128);
  float v0 = row[lane], v1 = row[lane + 64];
  float m = fmaxf(v0, v1);
  #pragma unroll
  for(int o = 1; o < 64; o <<= 1) m = fmaxf(m, __shfl_xor(m, o, 64));
  float e0 = __expf(v0 - m), e1 = __expf(v1 - m);
  float s = e0 + e1;
  #pragma unroll
  for(int o = 1; o < 64; o <<= 1) s += __shfl_xor(s, o, 64);
  float r0 = e0 / s, r1 = e1 / s;
  if(t < 16){
    size_t base = ((size_t)t*2048 + n) * 128;
    qbf[base + lane] = f2bf(v0); qbf[base + 64 + lane] = f2bf(v1);
    qlb[base + lane] = f2bf(r0); qlb[base + 64 + lane] = f2bf(r1);
  } else {
    int g = t - 16;
    size_t base = ((size_t)g*2048 + n) * 128;
    kbf[base + lane] = f2bf(v0); kbf[base + 64 + lane] = f2bf(v1);
    klf[base + lane] = r0;       klf[base + 64 + lane] = r1;
    klb[base + lane] = f2bf(r0); klb[base + 64 + lane] = f2bf(r1);
    float g0 = (fminf(v0, 0.f) - log1pf(__expf(-fabsf(v0)))) * (1.f/16.f);
    float g1 = (fminf(v1, 0.f) - log1pf(__expf(-fabsf(v1)))) * (1.f/16.f);
    glf[base + lane] = g0; glf[base + 64 + lane] = g1;
  }
}

// ---------------- V transpose: vT[g][d][n] = bf16(v[n][d]) ----------------
__global__ __launch_bounds__(256) void k_vt(const float* __restrict__ qkv, u16* __restrict__ vT){
  __shared__ float t[64][65];
  int nt = blockIdx.x, dt = blockIdx.y, g = blockIdx.z;
  int tid = threadIdx.x;
  {
    int r = tid >> 2, c0 = (tid & 3) * 16;
    const float* src = qkv + (size_t)(nt*64 + r)*3072 + 2560 + g*128 + dt*64 + c0;
    #pragma unroll
    for(int q = 0; q < 16; q += 4){
      f32x4 v = *(const f32x4*)(src + q);
      t[r][c0+q] = v[0]; t[r][c0+q+1] = v[1]; t[r][c0+q+2] = v[2]; t[r][c0+q+3] = v[3];
    }
  }
  __syncthreads();
  {
    int d = tid >> 2, c0 = (tid & 3) * 16;
    u16* dst = vT + ((size_t)g*128 + dt*64 + d)*2048 + (size_t)nt*64 + c0;
    #pragma unroll
    for(int half = 0; half < 2; ++half){
      int b = c0 + half*8;
      u32 w0 = (u32)f2bf(t[b+0][d]) | ((u32)f2bf(t[b+1][d]) << 16);
      u32 w1 = (u32)f2bf(t[b+2][d]) | ((u32)f2bf(t[b+3][d]) << 16);
      u32 w2 = (u32)f2bf(t[b+4][d]) | ((u32)f2bf(t[b+5][d]) << 16);
      u32 w3 = (u32)f2bf(t[b+6][d]) | ((u32)f2bf(t[b+7][d]) << 16);
      uint4 o = make_uint4(w0, w1, w2, w3);
      *(uint4*)(dst + half*8) = o;
    }
  }
}

// ---------------- prep1: per distinct chunk (g,c): A = strict(kb kl^T), Tinv by fwd subst ----------------
__global__ __launch_bounds__(256) void k_prep1(const float* __restrict__ klf, const float* __restrict__ glf,
                                               float* __restrict__ tinv){
  __shared__ float KlT[128][68];
  __shared__ float Kb[64][132];
  __shared__ float Am[64][68];
  __shared__ float XT[64][68];
  int idx = blockIdx.x, g = idx >> 5, c = idx & 31, tid = threadIdx.x;
  size_t base = ((size_t)g*2048 + c*64) * 128;
  {
    int r = tid >> 2, d0 = (tid & 3) * 32;
    #pragma unroll
    for(int dd = 0; dd < 32; dd += 4){
      f32x4 kv = *(const f32x4*)(klf + base + r*128 + d0 + dd);
      f32x4 gv = *(const f32x4*)(glf + base + r*128 + d0 + dd);
      KlT[d0+dd][r] = kv[0]; KlT[d0+dd+1][r] = kv[1]; KlT[d0+dd+2][r] = kv[2]; KlT[d0+dd+3][r] = kv[3];
      f32x4 kb = kv * gv;
      *(f32x4*)&Kb[r][d0+dd] = kb;
    }
  }
  __syncthreads();
  {
    int i = tid >> 2, j0 = (tid & 3) * 16;
    f32x4 s[4] = {};
    for(int d = 0; d < 128; ++d){
      float kb = Kb[i][d];
      #pragma unroll
      for(int q = 0; q < 4; ++q){
        f32x4 kl = *(const f32x4*)&KlT[d][j0 + q*4];
        s[q] += kb * kl;
      }
    }
    #pragma unroll
    for(int q = 0; q < 4; ++q) *(f32x4*)&Am[i][j0 + q*4] = s[q];
  }
  __syncthreads();
  if(tid < 64){
    int cc = tid;
    float x0 = (cc == 0) ? 1.f : 0.f;
    XT[cc][0] = x0;
    tinv[(size_t)idx*4096 + cc] = x0;
    for(int i = 1; i < 64; ++i){
      float s = (i == cc) ? 1.f : 0.f;
      int i4 = i & ~3;
      for(int jj = 0; jj < i4; jj += 4){
        f32x4 av = *(const f32x4*)&Am[i][jj];
        f32x4 xv = *(const f32x4*)&XT[cc][jj];
        s -= av[0]*xv[0] + av[1]*xv[1] + av[2]*xv[2] + av[3]*xv[3];
      }
      for(int jj = i4; jj < i; ++jj) s -= Am[i][jj] * XT[cc][jj];
      XT[cc][i] = s;
      tinv[(size_t)idx*4096 + i*64 + cc] = s;
    }
  }
}

// ---------------- prep2a: w = Tinv*kb, u0 = Tinv*vb ----------------
__global__ __launch_bounds__(256) void k_prep2a(const float* __restrict__ klf, const float* __restrict__ glf,
                                                const float* __restrict__ qkv, const float* __restrict__ tinv,
                                                float* __restrict__ wf, u16* __restrict__ wb, float* __restrict__ u0f){
  __shared__ float Ti[64][68];
  __shared__ float B1[64][132]; // kb
  __shared__ float B2[64][132]; // vb
  int idx = blockIdx.x, g = idx >> 5, c = idx & 31, tid = threadIdx.x;
  size_t base = ((size_t)g*2048 + c*64) * 128;
  {
    int r = tid >> 2, d0 = (tid & 3) * 32;
    #pragma unroll
    for(int dd = 0; dd < 32; dd += 4){
      f32x4 kv = *(const f32x4*)(klf + base + r*128 + d0 + dd);
      f32x4 gv = *(const f32x4*)(glf + base + r*128 + d0 + dd);
      f32x4 vv = *(const f32x4*)(qkv + (size_t)(c*64 + r)*3072 + 2560 + g*128 + d0 + dd);
      *(f32x4*)&B1[r][d0+dd] = kv * gv;
      *(f32x4*)&B2[r][d0+dd] = vv * gv;
    }
    int c0 = (tid & 3) * 16;
    #pragma unroll
    for(int q = 0; q < 16; q += 4)
      *(f32x4*)&Ti[r][c0+q] = *(const f32x4*)(tinv + (size_t)idx*4096 + r*64 + c0 + q);
  }
  __syncthreads();
  int i = tid >> 2, cc0 = (tid & 3) * 32;
  f32x4 wa[8] = {}; f32x4 ua[8] = {};
  for(int jj = 0; jj < 64; ++jj){
    float a = Ti[i][jj];
    #pragma unroll
    for(int q = 0; q < 8; ++q){
      f32x4 b1 = *(const f32x4*)&B1[jj][cc0 + q*4];
      f32x4 b2 = *(const f32x4*)&B2[jj][cc0 + q*4];
      wa[q] += a * b1; ua[q] += a * b2;
    }
  }
  #pragma unroll
  for(int q = 0; q < 8; ++q){
    *(f32x4*)(wf + (size_t)idx*8192 + i*128 + cc0 + q*4) = wa[q];
    *(f32x4*)(u0f + (size_t)idx*8192 + i*128 + cc0 + q*4) = ua[q];
    u32 w0 = (u32)f2bf(wa[q][0]) | ((u32)f2bf(wa[q][1]) << 16);
    u32 w1 = (u32)f2bf(wa[q][2]) | ((u32)f2bf(wa[q][3]) << 16);
    u32* dst = (u32*)(wb + (size_t)idx*8192 + i*128 + cc0 + q*4);
    dst[0] = w0; dst[1] = w1;
  }
}

// ---------------- prep2b: D = -(k^T w), BT = (k^T u0)^T; f32 masters + hi/lo mirrors ----------------
__global__ __launch_bounds__(256) void k_prep2b(const float* __restrict__ klf, const float* __restrict__ wf,
                                                const float* __restrict__ u0f,
                                                float* __restrict__ dF, u16* __restrict__ dH, u16* __restrict__ dL,
                                                u16* __restrict__ dTH, u16* __restrict__ dTL,
                                                float* __restrict__ btF, u16* __restrict__ btH, u16* __restrict__ btL){
  __shared__ float Kl[64][132];
  __shared__ float Wm[64][132];
  __shared__ float Um[64][132];
  int idx = blockIdx.x, g = idx >> 5, c = idx & 31, tid = threadIdx.x;
  size_t base = ((size_t)g*2048 + c*64) * 128;
  {
    int r = tid >> 2, d0 = (tid & 3) * 32;
    #pragma unroll
    for(int dd = 0; dd < 32; dd += 4){
      *(f32x4*)&Kl[r][d0+dd] = *(const f32x4*)(klf + base + r*128 + d0 + dd);
      *(f32x4*)&Wm[r][d0+dd] = *(const f32x4*)(wf + (size_t)idx*8192 + r*128 + d0 + dd);
      *(f32x4*)&Um[r][d0+dd] = *(const f32x4*)(u0f + (size_t)idx*8192 + r*128 + d0 + dd);
    }
  }
  __syncthreads();
  int a = tid >> 1, b0 = (tid & 1) * 64;
  f32x4 pa[16] = {}; f32x4 ca[16] = {};
  for(int r = 0; r < 64; ++r){
    float ka = Kl[r][a];
    float ua = Um[r][a];
    #pragma unroll
    for(int q = 0; q < 16; ++q){
      f32x4 wv = *(const f32x4*)&Wm[r][b0 + q*4];
      f32x4 kv = *(const f32x4*)&Kl[r][b0 + q*4];
      pa[q] += ka * wv;
      ca[q] += ua * kv;
    }
  }
  size_t ob = (size_t)idx * 16384;
  #pragma unroll
  for(int q = 0; q < 16; ++q){
    #pragma unroll
    for(int e = 0; e < 4; ++e){
      int b = b0 + q*4 + e;
      float dv = -pa[q][e];
      u16 dh, dl; splitbf(dv, dh, dl);
      dF[ob + a*128 + b] = dv;
      dH[ob + a*128 + b] = dh;
      dL[ob + a*128 + b] = dl;
      dTH[ob + (size_t)b*128 + a] = dh;
      dTL[ob + (size_t)b*128 + a] = dl;
      float cv = ca[q][e];
      u16 ch, cl; splitbf(cv, ch, cl);
      btF[ob + a*128 + b] = cv;
      btH[ob + a*128 + b] = ch;
      btL[ob + a*128 + b] = cl;
    }
  }
}

// ---------------- Kogge-Stone compose round (split-precision) ----------------
__global__ __launch_bounds__(256) void k_ks(
    const float* __restrict__ sDF, const u16* __restrict__ sDH, const u16* __restrict__ sDL,
    const u16* __restrict__ sDTH, const u16* __restrict__ sDTL,
    const float* __restrict__ sBF, const u16* __restrict__ sBH, const u16* __restrict__ sBL,
    float* __restrict__ dDF, u16* __restrict__ dDH, u16* __restrict__ dDL,
    u16* __restrict__ dDTH, u16* __restrict__ dDTL,
    float* __restrict__ dBF, u16* __restrict__ dBH, u16* __restrict__ dBL, int off){
  __shared__ float T[128][132];
  int c = blockIdx.x, g = blockIdx.y, z = blockIdx.z;
  int idx = g*32 + c, tid = threadIdx.x;
  size_t base = (size_t)idx * 16384;
  if(c < off){
    if(z == 0){
      for(int i = tid; i < 4096; i += 256) ((uint4*)(dDF + base))[i] = ((const uint4*)(sDF + base))[i];
      for(int i = tid; i < 2048; i += 256){
        ((uint4*)(dDH + base))[i] = ((const uint4*)(sDH + base))[i];
        ((uint4*)(dDL + base))[i] = ((const uint4*)(sDL + base))[i];
        ((uint4*)(dDTH + base))[i] = ((const uint4*)(sDTH + base))[i];
        ((uint4*)(dDTL + base))[i] = ((const uint4*)(sDTL + base))[i];
      }
    } else {
      for(int i = tid; i < 4096; i += 256) ((uint4*)(dBF + base))[i] = ((const uint4*)(sBF + base))[i];
      for(int i = tid; i < 2048; i += 256){
        ((uint4*)(dBH + base))[i] = ((const uint4*)(sBH + base))[i];
        ((uint4*)(dBL + base))[i] = ((const uint4*)(sBL + base))[i];
      }
    }
    return;
  }
  size_t blo = (size_t)(idx - off) * 16384;
  int lane = tid & 63, w = tid >> 6;
  const u16 *Ah, *Al, *Bh, *Bl;
  if(z == 0){ Ah = sDH + base; Al = sDL + base; Bh = sDTH + blo; Bl = sDTL + blo; }
  else      { Ah = sBH + blo;  Al = sBL + blo;  Bh = sDH + base; Bl = sDL + base; }
  f32x4 acc[2][8] = {};
  #pragma unroll
  for(int ks = 0; ks < 4; ++ks){
    bf16x8 ah[2], al[2], bh[8], bl[8];
    #pragma unroll
    for(int mt = 0; mt < 2; ++mt){
      int ro = (w*32 + mt*16 + (lane & 15))*128 + ks*32 + ((lane >> 4) << 3);
      ah[mt] = *(const bf16x8*)(Ah + ro);
      al[mt] = *(const bf16x8*)(Al + ro);
    }
    #pragma unroll
    for(int nt = 0; nt < 8; ++nt){
      int ro = (nt*16 + (lane & 15))*128 + ks*32 + ((lane >> 4) << 3);
      bh[nt] = *(const bf16x8*)(Bh + ro);
      bl[nt] = *(const bf16x8*)(Bl + ro);
    }
    #pragma unroll
    for(int mt = 0; mt < 2; ++mt)
      #pragma unroll
      for(int nt = 0; nt < 8; ++nt)
        acc[mt][nt] = MFMA16(ah[mt], bh[nt],
                      MFMA16(ah[mt], bl[nt],
                      MFMA16(al[mt], bh[nt], acc[mt][nt])));
  }
  if(z == 0){
    #pragma unroll
    for(int mt = 0; mt < 2; ++mt)
      #pragma unroll
      for(int nt = 0; nt < 8; ++nt)
        #pragma unroll
        for(int r = 0; r < 4; ++r){
          int row = w*32 + mt*16 + ((lane >> 4) << 2) + r;
          int col = nt*16 + (lane & 15);
          float v = acc[mt][nt][r] + sDF[base + row*128 + col] + sDF[blo + row*128 + col];
          dDF[base + row*128 + col] = v;
          u16 hi, lo; splitbf(v, hi, lo);
          dDH[base + row*128 + col] = hi;
          dDL[base + row*128 + col] = lo;
          T[row][col] = v;
        }
    __syncthreads();
    int tcol = tid >> 1, half = tid & 1;
    for(int m = 0; m < 64; ++m){
      float v = T[half*64 + m][tcol];
      u16 hi, lo; splitbf(v, hi, lo);
      dDTH[base + (size_t)tcol*128 + half*64 + m] = hi;
      dDTL[base + (size_t)tcol*128 + half*64 + m] = lo;
    }
  } else {
    #pragma unroll
    for(int mt = 0; mt < 2; ++mt)
      #pragma unroll
      for(int nt = 0; nt < 8; ++nt)
        #pragma unroll
        for(int r = 0; r < 4; ++r){
          int row = w*32 + mt*16 + ((lane >> 4) << 2) + r;
          int col = nt*16 + (lane & 15);
          float v = acc[mt][nt][r] + sBF[base + row*128 + col] + sBF[blo + row*128 + col];
          dBF[base + row*128 + col] = v;
          u16 hi, lo; splitbf(v, hi, lo);
          dBH[base + row*128 + col] = hi;
          dBL[base + row*128 + col] = lo;
        }
  }
}

// ---------------- generic compose: op_d = op_a AFTER op_b ----------------
__global__ __launch_bounds__(256) void k_comp(
    const float* __restrict__ bDF, const u16* __restrict__ bDH, const u16* __restrict__ bDL,
    const u16* __restrict__ bDTH, const u16* __restrict__ bDTL,
    const float* __restrict__ bBTF, const u16* __restrict__ bBTH, const u16* __restrict__ bBTL,
    float* __restrict__ pDF, u16* __restrict__ pDH, u16* __restrict__ pDL,
    u16* __restrict__ pDTH, u16* __restrict__ pDTL,
    float* __restrict__ pBTF, u16* __restrict__ pBTH, u16* __restrict__ pBTL,
    CompJobs jobs){
  __shared__ float T[128][132];
  int job = blockIdx.x, z = blockIdx.y, tid = threadIdx.x;
  int a = jobs.a[job], b = jobs.b[job], d = jobs.d[job] - 128;
  size_t ob = (size_t)d * 16384;
  int lane = tid & 63, w = tid >> 6;
  const u16 *Ah, *Al, *Bh, *Bl;
  const float *F1, *F2;
  if(z == 0){
    Ah = selu(bDH, pDH, a);  Al = selu(bDL, pDL, a);
    Bh = selu(bDTH, pDTH, b); Bl = selu(bDTL, pDTL, b);
    F1 = self32(bDF, pDF, a); F2 = self32(bDF, pDF, b);
  } else {
    Ah = selu(bBTH, pBTH, b); Al = selu(bBTL, pBTL, b);
    Bh = selu(bDH, pDH, a);   Bl = selu(bDL, pDL, a);
    F1 = self32(bBTF, pBTF, a); F2 = self32(bBTF, pBTF, b);
  }
  f32x4 acc[2][8] = {};
  #pragma unroll
  for(int ks = 0; ks < 4; ++ks){
    bf16x8 ah[2], al[2], bh[8], bl[8];
    #pragma unroll
    for(int mt = 0; mt < 2; ++mt){
      int ro = (w*32 + mt*16 + (lane & 15))*128 + ks*32 + ((lane >> 4) << 3);
      ah[mt] = *(const bf16x8*)(Ah + ro);
      al[mt] = *(const bf16x8*)(Al + ro);
    }
    #pragma unroll
    for(int nt = 0; nt < 8; ++nt){
      int ro = (nt*16 + (lane & 15))*128 + ks*32 + ((lane >> 4) << 3);
      bh[nt] = *(const bf16x8*)(Bh + ro);
      bl[nt] = *(const bf16x8*)(Bl + ro);
    }
    #pragma unroll
    for(int mt = 0; mt < 2; ++mt)
      #pragma unroll
      for(int nt = 0; nt < 8; ++nt)
        acc[mt][nt] = MFMA16(ah[mt], bh[nt],
                      MFMA16(ah[mt], bl[nt],
                      MFMA16(al[mt], bh[nt], acc[mt][nt])));
  }
  if(z == 0){
    #pragma unroll
    for(int mt = 0; mt < 2; ++mt)
      #pragma unroll
      for(int nt = 0; nt < 8; ++nt)
        #pragma unroll
        for(int r = 0; r < 4; ++r){
          int row = w*32 + mt*16 + ((lane >> 4) << 2) + r;
          int col = nt*16 + (lane & 15);
          float v = acc[mt][nt][r] + F1[row*128 + col] + F2[row*128 + col];
          pDF[ob + row*128 + col] = v;
          u16 hi, lo; splitbf(v, hi, lo);
          pDH[ob + row*128 + col] = hi;
          pDL[ob + row*128 + col] = lo;
          T[row][col] = v;
        }
    __syncthreads();
    int tcol = tid >> 1, half = tid & 1;
    for(int m = 0; m < 64; ++m){
      float v = T[half*64 + m][tcol];
      u16 hi, lo; splitbf(v, hi, lo);
      pDTH[ob + (size_t)tcol*128 + half*64 + m] = hi;
      pDTL[ob + (size_t)tcol*128 + half*64 + m] = lo;
    }
  } else {
    #pragma unroll
    for(int mt = 0; mt < 2; ++mt)
      #pragma unroll
      for(int nt = 0; nt < 8; ++nt)
        #pragma unroll
        for(int r = 0; r < 4; ++r){
          int row = w*32 + mt*16 + ((lane >> 4) << 2) + r;
          int col = nt*16 + (lane & 15);
          float v = acc[mt][nt][r] + F1[row*128 + col] + F2[row*128 + col];
          pBTF[ob + row*128 + col] = v;
          u16 hi, lo; splitbf(v, hi, lo);
          pBTH[ob + row*128 + col] = hi;
          pBTL[ob + row*128 + col] = lo;
        }
  }
}

// ---------------- head starts (parallel) ----------------
__global__ __launch_bounds__(256) void k_heads(
    const u16* __restrict__ bDH, const u16* __restrict__ bDL,
    const float* __restrict__ bBTF, const u16* __restrict__ bBTH, const u16* __restrict__ bBTL,
    const u16* __restrict__ pDH, const u16* __restrict__ pDL,
    const float* __restrict__ pBTF, const u16* __restrict__ pBTH, const u16* __restrict__ pBTL,
    float* __restrict__ ttF, u16* __restrict__ ttH, u16* __restrict__ ttL, u16* __restrict__ sj){
  int h = blockIdx.x, g = h >> 2, i = h & 3;
  int tid = threadIdx.x, lane = tid & 63, w = tid >> 6;
  int psi = (g == 0) ? -1 : (g == 1 ? 136 : (g == 2 ? 140 : 142));
  int phi = (i == 0) ? -1 : (i == 1 ? g*32 + 31 : (i == 2 ? 128 + g : 132 + g));
  f32x4 acc[2][8] = {};
  if(psi >= 0 && phi >= 0){
    const u16* Ah = selu(bBTH, pBTH, psi);
    const u16* Al = selu(bBTL, pBTL, psi);
    const u16* Bh = selu(bDH, pDH, phi);
    const u16* Bl = selu(bDL, pDL, phi);
    #pragma unroll
    for(int ks = 0; ks < 4; ++ks){
      bf16x8 ah[2], al[2], bh[8], bl[8];
      #pragma unroll
      for(int mt = 0; mt < 2; ++mt){
        int ro = (w*32 + mt*16 + (lane & 15))*128 + ks*32 + ((lane >> 4) << 3);
        ah[mt] = *(const bf16x8*)(Ah + ro);
        al[mt] = *(const bf16x8*)(Al + ro);
      }
      #pragma unroll
      for(int nt = 0; nt < 8; ++nt){
        int ro = (nt*16 + (lane & 15))*128 + ks*32 + ((lane >> 4) << 3);
        bh[nt] = *(const bf16x8*)(Bh + ro);
        bl[nt] = *(const bf16x8*)(Bl + ro);
      }
      #pragma unroll
      for(int mt = 0; mt < 2; ++mt)
        #pragma unroll
        for(int nt = 0; nt < 8; ++nt)
          acc[mt][nt] = MFMA16(ah[mt], bh[nt],
                        MFMA16(ah[mt], bl[nt],
                        MFMA16(al[mt], bh[nt], acc[mt][nt])));
    }
  }
  const float* Pf = (psi >= 0) ? self32(bBTF, pBTF, psi) : nullptr;
  const float* Ff = (phi >= 0) ? self32(bBTF, pBTF, phi) : nullptr;
  #pragma unroll
  for(int mt = 0; mt < 2; ++mt)
    #pragma unroll
    for(int nt = 0; nt < 8; ++nt)
      #pragma unroll
      for(int r = 0; r < 4; ++r){
        int row = w*32 + mt*16 + ((lane >> 4) << 2) + r;
        int col = nt*16 + (lane & 15);
        float v = acc[mt][nt][r];
        if(Pf) v += Pf[row*128 + col];
        if(Ff) v += Ff[row*128 + col];
        u16 hi, lo; splitbf(v, hi, lo);
        size_t o = (size_t)h*16384 + row*128 + col;
        ttF[o] = v; ttH[o] = hi; ttL[o] = lo;
        sj[(size_t)(h*32)*16384 + row*128 + col] = hi;
      }
}

// ---------------- expand: ST_{h,c} = TT_h + nt(TT_h, Dg_{c-1}) + BTg_{c-1} ----------------
__global__ __launch_bounds__(256) void k_expand(const u16* __restrict__ bDH, const u16* __restrict__ bDL,
                                                const float* __restrict__ bBF, const float* __restrict__ ttF,
                                                const u16* __restrict__ ttH, const u16* __restrict__ ttL,
                                                u16* __restrict__ sj){
  int j = blockIdx.x;
  int c = j & 31;
  if(c == 0) return;
  int h = j >> 5, g = h >> 2;
  size_t obase = (size_t)j * 16384;
  size_t mb = (size_t)(g*32 + c - 1) * 16384;
  size_t tb = (size_t)h * 16384;
  int tid = threadIdx.x, lane = tid & 63, w = tid >> 6;
  f32x4 acc[2][8] = {};
  #pragma unroll
  for(int ks = 0; ks < 4; ++ks){
    bf16x8 ah[2], al[2], bh[8], bl[8];
    #pragma unroll
    for(int mt = 0; mt < 2; ++mt){
      int ro = (w*32 + mt*16 + (lane & 15))*128 + ks*32 + ((lane >> 4) << 3);
      ah[mt] = *(const bf16x8*)(ttH + tb + ro);
      al[mt] = *(const bf16x8*)(ttL + tb + ro);
    }
    #pragma unroll
    for(int nt = 0; nt < 8; ++nt){
      int ro = (nt*16 + (lane & 15))*128 + ks*32 + ((lane >> 4) << 3);
      bh[nt] = *(const bf16x8*)(bDH + mb + ro);
      bl[nt] = *(const bf16x8*)(bDL + mb + ro);
    }
    #pragma unroll
    for(int mt = 0; mt < 2; ++mt)
      #pragma unroll
      for(int nt = 0; nt < 8; ++nt)
        acc[mt][nt] = MFMA16(ah[mt], bh[nt],
                      MFMA16(ah[mt], bl[nt],
                      MFMA16(al[mt], bh[nt], acc[mt][nt])));
  }
  #pragma unroll
  for(int mt = 0; mt < 2; ++mt)
    #pragma unroll
    for(int nt = 0; nt < 8; ++nt)
      #pragma unroll
      for(int r = 0; r < 4; ++r){
        int row = w*32 + mt*16 + ((lane >> 4) << 2) + r;
        int col = nt*16 + (lane & 15);
        float v = acc[mt][nt][r] + ttF[tb + row*128 + col] + bBF[mb + row*128 + col];
        sj[obase + row*128 + col] = f2bf(v);
      }
}

// ---------------- o_lin per (h,c): o = q@S + tril(q k^T)@(u0 - w@S); omix = 0.5*o ----------------
__global__ __launch_bounds__(256) void k_olin(const u16* __restrict__ qlb, const u16* __restrict__ klb,
                                              const u16* __restrict__ wb, const float* __restrict__ u0f,
                                              const u16* __restrict__ sj, float* __restrict__ omix){
  __shared__ u16 ut[128*64];    // u_i^T [d][kv], swizzled
  __shared__ u16 pl[4][16*64];  // per-wave masked scores, swizzled
  int j = blockIdx.x;
  int h = j >> 5, c = j & 31, g = h >> 2, idx = g*32 + c;
  int tid = threadIdx.x, lane = tid & 63, w = tid >> 6;
  const u16* Sj = sj + (size_t)j * 16384;
  const u16* Q  = qlb + ((size_t)h*2048 + c*64) * 128;
  const u16* Kc = klb + ((size_t)g*2048 + c*64) * 128;
  const u16* W  = wb + (size_t)idx * 8192;
  const float* U0 = u0f + (size_t)idx * 8192;
  bf16x8 aq[4], aw[4];
  #pragma unroll
  for(int ks = 0; ks < 4; ++ks){
    aq[ks] = *(const bf16x8*)(Q + (w*16 + (lane & 15))*128 + ks*32 + ((lane >> 4) << 3));
    aw[ks] = *(const bf16x8*)(W + (w*16 + (lane & 15))*128 + ks*32 + ((lane >> 4) << 3));
  }
  f32x4 t1[8] = {}, ui[8] = {};
  #pragma unroll
  for(int ks = 0; ks < 4; ++ks)
    #pragma unroll
    for(int nt = 0; nt < 8; ++nt){
      bf16x8 b = *(const bf16x8*)(Sj + (nt*16 + (lane & 15))*128 + ks*32 + ((lane >> 4) << 3));
      t1[nt] = MFMA16(aq[ks], b, t1[nt]);
      ui[nt] = MFMA16(aw[ks], b, ui[nt]);
    }
  f32x4 sc[4] = {};
  #pragma unroll
  for(int ks = 0; ks < 4; ++ks)
    #pragma unroll
    for(int nt = 0; nt < 4; ++nt){
      bf16x8 b = *(const bf16x8*)(Kc + (nt*16 + (lane & 15))*128 + ks*32 + ((lane >> 4) << 3));
      sc[nt] = MFMA16(aq[ks], b, sc[nt]);
    }
  // masked scores to per-wave LDS
  #pragma unroll
  for(int nt = 0; nt < 4; ++nt)
    #pragma unroll
    for(int r = 0; r < 4; ++r){
      int row = ((lane >> 4) << 2) + r;
      int col = nt*16 + (lane & 15);
      int grow = w*16 + row;
      float v = (col <= grow) ? sc[nt][r] : 0.f;
      int bo = (row*128 + col*2) ^ ((row & 7) << 4);
      *(u16*)((char*)&pl[w][0] + bo) = f2bf(v);
    }
  // u_i = u0 - w@S, transposed into LDS
  #pragma unroll
  for(int nt = 0; nt < 8; ++nt)
    #pragma unroll
    for(int r = 0; r < 4; ++r){
      int kv = w*16 + ((lane >> 4) << 2) + r;
      int d  = nt*16 + (lane & 15);
      float v = U0[kv*128 + d] - ui[nt][r];
      int bo = (d*128 + kv*2) ^ ((d & 7) << 4);
      *(u16*)((char*)ut + bo) = f2bf(v);
    }
  __syncthreads();
  f32x4 o2[8] = {};
  #pragma unroll
  for(int ks2 = 0; ks2 < 2; ++ks2){
    int row = lane & 15;
    int boA = (row*128 + ks2*64 + ((lane >> 4) << 4)) ^ ((row & 7) << 4);
    bf16x8 a = *(const bf16x8*)((const char*)&pl[w][0] + boA);
    #pragma unroll
    for(int nt = 0; nt < 8; ++nt){
      int d = nt*16 + (lane & 15);
      int boB = (d*128 + ks2*64 + ((lane >> 4) << 4)) ^ ((d & 7) << 4);
      bf16x8 b = *(const bf16x8*)((const char*)ut + boB);
      o2[nt] = MFMA16(a, b, o2[nt]);
    }
  }
  #pragma unroll
  for(int nt = 0; nt < 8; ++nt)
    #pragma unroll
    for(int r = 0; r < 4; ++r){
      int grow = c*64 + w*16 + ((lane >> 4) << 2) + r;
      int d = nt*16 + (lane & 15);
      omix[(size_t)grow*2048 + h*128 + d] = 0.5f * (t1[nt][r] + o2[nt][r]);
    }
}

// ---------------- base causal attention v3: 128 q-rows/block (32/wave), dbuf P-LDS, K prefetch ----------------
// bid<64: (h, qB<4) single segment -> finalize into omix.  bid>=64: slot = bid-64 = h*36 + j.
__global__ __launch_bounds__(256) void k_attn(const u16* __restrict__ qbf, const u16* __restrict__ kbf,
                                              const u16* __restrict__ vT, float* __restrict__ omix,
                                              float* __restrict__ part1, float* __restrict__ part2){
  __shared__ u16 pl[4][2560]; // per wave: 2 bufs x 32 rows x 80B
  int bid = blockIdx.x;
  int h, qB, kt0, kt1, slot = -1;
  if(bid < 64){ h = bid >> 2; qB = bid & 3; kt0 = 0; kt1 = 4*(qB+1); }
  else {
    int t = bid - 64; h = t / 36; int j = t % 36; int seg;
    if(j < 8){ qB = 4 + (j >> 1); seg = j & 1; }
    else if(j < 20){ int q = j - 8; qB = 8 + q/3; seg = q - (qB-8)*3; }
    else { int q = j - 20; qB = 12 + (q >> 2); seg = q & 3; }
    slot = t;
    kt0 = seg*16;
    int full = 4*(qB+1);
    kt1 = (kt0 + 16 < full) ? kt0 + 16 : full;
  }
  int g = h >> 2;
  int tid = threadIdx.x, lane = tid & 63, w = tid >> 6;
  const u16* K = kbf + (size_t)g*2048*128;
  const u16* V = vT + (size_t)g*128*2048;
  bf16x8 aq[2][4];
  #pragma unroll
  for(int m = 0; m < 2; ++m){
    const u16* Q = qbf + ((size_t)h*2048 + qB*128 + w*32 + m*16) * 128;
    #pragma unroll
    for(int ks = 0; ks < 4; ++ks)
      aq[m][ks] = *(const bf16x8*)(Q + (lane & 15)*128 + ks*32 + ((lane >> 4) << 3));
  }
  f32x4 acc[2][8] = {};
  float lsum[2][4] = {};
  const float scale = 0.08838834764831845f;
  int qr0[2];
  #pragma unroll
  for(int m = 0; m < 2; ++m) qr0[m] = qB*128 + w*32 + m*16 + ((lane >> 4) << 2);
  u16* plw = &pl[w][0];
  bf16x8 kb[8];
  #pragma unroll
  for(int ct = 0; ct < 2; ++ct)
    #pragma unroll
    for(int ks = 0; ks < 4; ++ks)
      kb[ct*4+ks] = *(const bf16x8*)(K + (size_t)(kt0*32 + ct*16 + (lane & 15))*128 + ks*32 + ((lane >> 4) << 3));
  int buf = 0;
  for(int kt = kt0; kt < kt1; ++kt){
    // QK^T for both strips (shared K frags)
    f32x4 s[2][2] = {};
    #pragma unroll
    for(int m = 0; m < 2; ++m)
      #pragma unroll
      for(int ct = 0; ct < 2; ++ct)
        #pragma unroll
        for(int ks = 0; ks < 4; ++ks)
          s[m][ct] = MFMA16(aq[m][ks], kb[ct*4+ks], s[m][ct]);
    // prefetch next K tile while exp/LDS/PV run
    bf16x8 kbn[8];
    if(kt + 1 < kt1){
      #pragma unroll
      for(int ct = 0; ct < 2; ++ct)
        #pragma unroll
        for(int ks = 0; ks < 4; ++ks)
          kbn[ct*4+ks] = *(const bf16x8*)(K + (size_t)((kt+1)*32 + ct*16 + (lane & 15))*128 + ks*32 + ((lane >> 4) << 3));
    }
    // V loads (independent of scores)
    bf16x8 bv[8];
    #pragma unroll
    for(int nt = 0; nt < 8; ++nt)
      bv[nt] = *(const bf16x8*)(V + (size_t)(nt*16 + (lane & 15))*2048 + kt*32 + ((lane >> 4) << 3));
    // unnormalized p = exp(s*scale) with causal mask; scores are O(+-5) -> no overflow
    #pragma unroll
    for(int m = 0; m < 2; ++m)
      #pragma unroll
      for(int ct = 0; ct < 2; ++ct)
        #pragma unroll
        for(int r = 0; r < 4; ++r){
          int col = kt*32 + ct*16 + (lane & 15);
          float p = (col <= qr0[m] + r) ? __expf(s[m][ct][r] * scale) : 0.f;
          lsum[m][r] += p;
          int row = m*16 + ((lane >> 4) << 2) + r;
          *(u16*)((char*)plw + buf*2560 + row*80 + (ct*16 + (lane & 15))*2) = f2bf(p);
        }
    #pragma unroll
    for(int m = 0; m < 2; ++m){
      bf16x8 ap = *(const bf16x8*)((const char*)plw + buf*2560 + (m*16 + (lane & 15))*80 + ((lane >> 4) << 4));
      #pragma unroll
      for(int nt = 0; nt < 8; ++nt)
        acc[m][nt] = MFMA16(ap, bv[nt], acc[m][nt]);
    }
    #pragma unroll
    for(int i = 0; i < 8; ++i) kb[i] = kbn[i];
    buf ^= 1;
  }
  // one final 16-lane reduction of the row-sums
  #pragma unroll
  for(int m = 0; m < 2; ++m)
    #pragma unroll
    for(int r = 0; r < 4; ++r){
      float v = lsum[m][r];
      v += __shfl_xor(v, 1, 64); v += __shfl_xor(v, 2, 64);
      v += __shfl_xor(v, 4, 64); v += __shfl_xor(v, 8, 64);
      lsum[m][r] = v;
    }
  if(slot < 0){
    #pragma unroll
    for(int m = 0; m < 2; ++m)
      #pragma unroll
      for(int nt = 0; nt < 8; ++nt)
        #pragma unroll
        for(int r = 0; r < 4; ++r){
          int row = qB*128 + w*32 + m*16 + ((lane >> 4) << 2) + r;
          int d = nt*16 + (lane & 15);
          size_t o = (size_t)row*2048 + h*128 + d;
          omix[o] += 0.5f * acc[m][nt][r] / lsum[m][r];
        }
  } else {
    float* P = slotp(part1, part2, slot);
    #pragma unroll
    for(int m = 0; m < 2; ++m)
      #pragma unroll
      for(int nt = 0; nt < 8; ++nt)
        #pragma unroll
        for(int r = 0; r < 4; ++r){
          int row = w*32 + m*16 + ((lane >> 4) << 2) + r;
          int d = nt*16 + (lane & 15);
          P[(size_t)row*128 + d] = acc[m][nt][r];
        }
    if((lane & 15) == 0)
      #pragma unroll
      for(int m = 0; m < 2; ++m)
        #pragma unroll
        for(int r = 0; r < 4; ++r)
          P[16384 + w*32 + m*16 + ((lane >> 4) << 2) + r] = lsum[m][r];
  }
}

// ---------------- combine attention K-segments (2..4): omix += 0.5*sum(acc)/sum(l) ----------------
__global__ __launch_bounds__(256) void k_acomb(const float* __restrict__ part1, const float* __restrict__ part2,
                                               float* __restrict__ omix){
  int bid = blockIdx.x;             // h*12 + (qB-4)
  int h = bid / 12, qx = bid % 12, qB = 4 + qx;
  int nseg = (qB >= 12) ? 4 : (qB >= 8) ? 3 : 2;
  int off = (qB < 8) ? (qB-4)*2 : (qB < 12) ? 8 + (qB-8)*3 : 20 + (qB-12)*4;
  int s0 = h*36 + off;
  int tid = threadIdx.x;
  #pragma unroll
  for(int it = 0; it < 16; ++it){
    int i = it*1024 + tid*4;
    int row = i >> 7;
    f32x4 a = {};
    float l = 0.f;
    for(int s = 0; s < nseg; ++s){
      const float* P = slotpc(part1, part2, s0 + s);
      a += *(const f32x4*)(P + i);
      l += P[16384 + row];
    }
    float* dst = omix + (size_t)(qB*128 + row)*2048 + h*128 + (i & 127);
    f32x4 cur = *(const f32x4*)dst;
    *(f32x4*)dst = cur + a * (0.5f / l);
  }
}

// ---------------- launch ----------------
extern "C" void kernel_launch(void* const* d_in, const int* in_sizes, int n_in,
                              void* d_out, int out_size, void* d_ws, size_t ws_size,
                              hipStream_t stream){
  (void)in_sizes; (void)n_in; (void)out_size; (void)ws_size;
  const float* hs = (const float*)d_in[0];
  const float* Wq = (const float*)d_in[1];
  const float* Wk = (const float*)d_in[2];
  const float* Wv = (const float*)d_in[3];
  const float* Wo = (const float*)d_in[4];
  float* out = (float*)d_out;
  char* ws = (char*)d_ws;

  u16*   hs_bf   = (u16*)(ws + OF_HSBF);
  u16*   wqkv_bf = (u16*)(ws + OF_WQKVBF);
  u16*   wo_bf   = (u16*)(ws + OF_WOBF);
  float* qkv     = (float*)(ws + OF_QKV);
  u16*   qbf     = (u16*)(ws + OF_QBF);
  u16*   kbf     = (u16*)(ws + OF_KBF);
  u16*   vT      = (u16*)(ws + OF_VT);
  u16*   qlb     = (u16*)(ws + OF_QLB);
  float* klf     = (float*)(ws + OF_KLF);
  u16*   klb     = (u16*)(ws + OF_KLB);
  float* glf     = (float*)(ws + OF_GLF);
  float* tinvb   = (float*)(ws + OF_TINV);
  float* wf      = (float*)(ws + OF_WF);
  u16*   wb      = (u16*)(ws + OF_WB);
  float* u0f     = (float*)(ws + OF_U0);
  u16*   sjb     = (u16*)(ws + OF_SJ);
  float* omix    = (float*)(ws + OF_OMIX);
  u16*   omix_bf = (u16*)(ws + OF_OMIXB);
  // scan buffers
  float* aDF  = (float*)(ws + OF_ADF);
  u16*   aDH  = (u16*)(ws + OF_ADH);
  u16*   aDL  = (u16*)(ws + OF_ADL);
  u16*   aDTH = (u16*)(ws + OF_ADTH);
  u16*   aDTL = (u16*)(ws + OF_ADTL);
  float* aBTF = (float*)(ws + OF_ABTF);
  u16*   aBTH = (u16*)(ws + OF_ABTH);
  u16*   aBTL = (u16*)(ws + OF_ABTL);
  float* bDF  = (float*)(ws + OF_BDF);
  u16*   bDH  = (u16*)(ws + OF_BDH);
  u16*   bDL  = (u16*)(ws + OF_BDL);
  u16*   bDTH = (u16*)(ws + OF_BDTH);
  u16*   bDTL = (u16*)(ws + OF_BDTL);
  float* bBTF = (float*)(ws + OF_BBTF);
  u16*   bBTH = (u16*)(ws + OF_BBTH);
  u16*   bBTL = (u16*)(ws + OF_BBTL);
  float* ttF  = (float*)(ws + OF_TTF);
  u16*   ttH  = (u16*)(ws + OF_TTH);
  u16*   ttL  = (u16*)(ws + OF_TTL);
  // op pool
  float* pDF  = (float*)(ws + OF_PDF);
  float* pBTF = (float*)(ws + OF_PBTF);
  u16*   pDH  = (u16*)(ws + OF_PDH);
  u16*   pDL  = (u16*)(ws + OF_PDL);
  u16*   pDTH = (u16*)(ws + OF_PDTH);
  u16*   pDTL = (u16*)(ws + OF_PDTL);
  u16*   pBTH = (u16*)(ws + OF_PBTH);
  u16*   pBTL = (u16*)(ws + OF_PBTL);
  float* apart1 = (float*)(ws + OF_APART1);
  float* apart2 = (float*)(ws + OF_APART2);

  k_f2b<<<4096, 256, 0, stream>>>(hs, hs_bf, 4194304);
  k_f2b<<<4096, 256, 0, stream>>>(Wq, wqkv_bf, 4194304);
  k_f2b<<<1024, 256, 0, stream>>>(Wk, wqkv_bf + 2048*2048, 1048576);
  k_f2b<<<1024, 256, 0, stream>>>(Wv, wqkv_bf + 2560*2048, 1048576);
  k_f2b<<<4096, 256, 0, stream>>>(Wo, wo_bf, 4194304);

  k_gemm<<<dim3(24, 16), 256, 0, stream>>>(hs_bf, wqkv_bf, qkv, 2048, 3072);
  k_linprep<<<10240, 256, 0, stream>>>(qkv, qbf, qlb, kbf, klf, klb, glf);
  k_vt<<<dim3(32, 2, 4), 256, 0, stream>>>(qkv, vT);

  k_prep1<<<128, 256, 0, stream>>>(klf, glf, tinvb);
  k_prep2a<<<128, 256, 0, stream>>>(klf, glf, qkv, tinvb, wf, wb, u0f);
  k_prep2b<<<128, 256, 0, stream>>>(klf, wf, u0f, aDF, aDH, aDL, aDTH, aDTL, aBTF, aBTH, aBTL);

  // Kogge-Stone prefix-compose within groups (5 rounds, ping-pong; result in side B)
  k_ks<<<dim3(32, 4, 2), 256, 0, stream>>>(aDF, aDH, aDL, aDTH, aDTL, aBTF, aBTH, aBTL,
                                           bDF, bDH, bDL, bDTH, bDTL, bBTF, bBTH, bBTL, 1);
  k_ks<<<dim3(32, 4, 2), 256, 0, stream>>>(bDF, bDH, bDL, bDTH, bDTL, bBTF, bBTH, bBTL,
                                           aDF, aDH, aDL, aDTH, aDTL, aBTF, aBTH, aBTL, 2);
  k_ks<<<dim3(32, 4, 2), 256, 0, stream>>>(aDF, aDH, aDL, aDTH, aDTL, aBTF, aBTH, aBTL,
                                           bDF, bDH, bDL, bDTH, bDTL, bBTF, bBTH, bBTL, 4);
  k_ks<<<dim3(32, 4, 2), 256, 0, stream>>>(bDF, bDH, bDL, bDTH, bDTL, bBTF, bBTH, bBTL,
                                           aDF, aDH, aDL, aDTH, aDTL, aBTF, aBTH, aBTL, 8);
  k_ks<<<dim3(32, 4, 2), 256, 0, stream>>>(aDF, aDH, aDL, aDTH, aDTL, aBTF, aBTH, aBTL,
                                           bDF, bDH, bDL, bDTH, bDTL, bBTF, bBTH, bBTL, 16);

  // group-operator powers + group-level prefix (pool slots; op_d = op_a AFTER op_b)
  CompJobs j1{}; // Phi_g^2
  for(int g = 0; g < 4; ++g){ j1.a[g] = g*32+31; j1.b[g] = g*32+31; j1.d[g] = 128+g; }
  k_comp<<<dim3(4, 2), 256, 0, stream>>>(bDF, bDH, bDL, bDTH, bDTL, bBTF, bBTH, bBTL,
                                         pDF, pDH, pDL, pDTH, pDTL, pBTF, pBTH, pBTL, j1);
  CompJobs j2{}; // Phi^3, Phi^4
  for(int g = 0; g < 4; ++g){
    j2.a[g]   = 128+g; j2.b[g]   = g*32+31; j2.d[g]   = 132+g;
    j2.a[4+g] = 128+g; j2.b[4+g] = 128+g;   j2.d[4+g] = 136+g;
  }
  k_comp<<<dim3(8, 2), 256, 0, stream>>>(bDF, bDH, bDL, bDTH, bDTL, bBTF, bBTH, bBTL,
                                         pDF, pDH, pDL, pDTH, pDTL, pBTF, pBTH, pBTL, j2);
  CompJobs j3{}; // Psi2; T
  j3.a[0] = 137; j3.b[0] = 136; j3.d[0] = 140;
  j3.a[1] = 138; j3.b[1] = 137; j3.d[1] = 141;
  k_comp<<<dim3(2, 2), 256, 0, stream>>>(bDF, bDH, bDL, bDTH, bDTL, bBTF, bBTH, bBTL,
                                         pDF, pDH, pDL, pDTH, pDTL, pBTF, pBTH, pBTL, j3);
  CompJobs j4{}; // Psi3
  j4.a[0] = 141; j4.b[0] = 136; j4.d[0] = 142;
  k_comp<<<dim3(1, 2), 256, 0, stream>>>(bDF, bDH, bDL, bDTH, bDTL, bBTF, bBTH, bBTL,
                                         pDF, pDH, pDL, pDTH, pDTL, pBTF, pBTH, pBTL, j4);

  k_heads<<<16, 256, 0, stream>>>(bDH, bDL, bBTF, bBTH, bBTL,
                                  pDH, pDL, pBTF, pBTH, pBTL, ttF, ttH, ttL, sjb);
  k_expand<<<512, 256, 0, stream>>>(bDH, bDL, bBTF, ttF, ttH, ttL, sjb);

  k_olin<<<512, 256, 0, stream>>>(qlb, klb, wb, u0f, sjb, omix);
  k_attn<<<640, 256, 0, stream>>>(qbf, kbf, vT, omix, apart1, apart2);
  k_acomb<<<192, 256, 0, stream>>>(apart1, apart2, omix);

  k_f2b<<<4096, 256, 0, stream>>>(omix, omix_bf, 4194304);
  k_gemm<<<dim3(16, 16), 256, 0, stream>>>(omix_bf, wo_bf, out, 2048, 2048);
}